// Round 10
// baseline (339.075 us; speedup 1.0000x reference)
//
#include <hip/hip_runtime.h>
#include <hip/hip_bf16.h>

#define NB 2
#define NQ 20000
#define DM 64
#define NH 8
#define NL 5
#define NP 4
#define LIN 45109
#define FFN 1024

typedef __attribute__((ext_vector_type(8))) short short8;
typedef __attribute__((ext_vector_type(4))) float f32x4;

__device__ __forceinline__ float lo16f(unsigned u) { return __uint_as_float(u << 16); }
__device__ __forceinline__ float hi16f(unsigned u) { return __uint_as_float(u & 0xffff0000u); }

// ---- kernel 1: val[row,c] = (dvf[row,:] @ Wv + bv)[c]; handles 1 or 2 batches ----
__global__ void val_proj_kernel(const float* __restrict__ dvf,
                                const float* __restrict__ Wv,
                                const float* __restrict__ bv,
                                __hip_bfloat16* __restrict__ valA,
                                __hip_bfloat16* __restrict__ valB,
                                int rows) {
    const int lane = threadIdx.x & 63;
    const int row = blockIdx.x * 4 + (threadIdx.x >> 6);
    if (row >= rows) return;
    float mine = dvf[(size_t)row * DM + lane];
    float acc = bv[lane];
#pragma unroll 8
    for (int k = 0; k < DM; k++) {
        float vk = __shfl(mine, k, 64);
        acc = fmaf(vk, Wv[k * DM + lane], acc);
    }
    __hip_bfloat16* dst = (row < LIN) ? (valA + (size_t)row * DM)
                                      : (valB + (size_t)(row - LIN) * DM);
    dst[lane] = __float2bfloat16(acc);
}

// ---- kernel 2: pack W1/W2/[Wo|Wa] to bf16 MFMA B-fragment order ----
// B-frag 16x16x32: lane holds B[k=(lane>>4)*8+j][n=lane&15], j=0..7.
__global__ void pack_kernel(const float* __restrict__ W1, const float* __restrict__ W2,
                            const float* __restrict__ Wo, const float* __restrict__ Wa,
                            __hip_bfloat16* __restrict__ W1p, __hip_bfloat16* __restrict__ W2p,
                            __hip_bfloat16* __restrict__ Woap) {
    const int t = blockIdx.x * 256 + threadIdx.x;
    const int lane = t & 63;
    const int m = lane & 15, qd = lane >> 4;
    const int seg = t >> 6;
    if (seg < 128) {                  // W1 (64x1024): 64 ntiles x 2 kchunks
        const int nt = seg >> 1, kc = seg & 1;
        const int n = nt * 16 + m, kb = kc * 32 + qd * 8;
        __hip_bfloat16* dst = W1p + ((size_t)seg * 64 + lane) * 8;
#pragma unroll
        for (int j = 0; j < 8; j++) dst[j] = __float2bfloat16(W1[(size_t)(kb + j) * FFN + n]);
    } else if (seg < 256) {           // W2 (1024x64): 4 ntiles x 32 kchunks
        const int sl = seg - 128;
        const int nt = sl >> 5, kc = sl & 31;
        const int n = nt * 16 + m, kb = kc * 32 + qd * 8;
        __hip_bfloat16* dst = W2p + ((size_t)sl * 64 + lane) * 8;
#pragma unroll
        for (int j = 0; j < 8; j++) dst[j] = __float2bfloat16(W2[(size_t)(kb + j) * DM + n]);
    } else if (seg < 316) {           // [Wo|Wa] (64x480): 30 ntiles x 2 kchunks
        const int sl = seg - 256;
        const int nt = sl >> 1, kc = sl & 1;
        const int n = nt * 16 + m, kb = kc * 32 + qd * 8;
        __hip_bfloat16* dst = Woap + ((size_t)sl * 64 + lane) * 8;
#pragma unroll
        for (int j = 0; j < 8; j++) {
            const int k = kb + j;
            const float v = (n < 320) ? Wo[(size_t)k * 320 + n] : Wa[(size_t)k * 160 + (n - 320)];
            dst[j] = __float2bfloat16(v);
        }
    }
}

// ---- kernel 3: attn, 4 queries/block; B via MFMA; C via row-oriented gathers ----
__global__ void __launch_bounds__(256)
attn4_kernel(const float* __restrict__ q_feat,
             const float* __restrict__ ref_pts,
             const float* __restrict__ q_pos,
             const __hip_bfloat16* __restrict__ Woap,
             const float* __restrict__ bo, const float* __restrict__ ba,
             const float* __restrict__ Wout, const float* __restrict__ bout,
             const float* __restrict__ g1, const float* __restrict__ b1,
             const __hip_bfloat16* __restrict__ valA,
             const __hip_bfloat16* __restrict__ valB,
             int qoff,
             float* __restrict__ xout) {
    __shared__ __align__(16) __hip_bfloat16 qb[16][72];   // A-frag; rows 4-15 zero
    __shared__ __align__(16) float offs[4][321];
    __shared__ __align__(16) float aws[4][161];
    __shared__ __align__(16) float refs[4][2];
    // per-corner descriptors: (byte offset, f32 weight); head stride 82 (bank spread)
    __shared__ __align__(16) int2 desc[4 * 8 * 82];       // 20992 B
    __shared__ __align__(16) float outv[4][64];

    const int tid = threadIdx.x;
    const int lane = tid & 63;
    const int w = tid >> 6;
    const int m16 = lane & 15, qd = lane >> 4;
    const int q0 = qoff + blockIdx.x * 4;                 // all 4 queries same batch
    const int qi = q0 + w;

    const int sz[NL]  = {184, 92, 46, 23, 12};
    const int lsi[NL] = {0, 33856, 42320, 44436, 44965};

    const __hip_bfloat16* valp = (q0 >= NQ) ? valB : valA;

    // ---- phase A: wave w owns query w ----
    const float qf = q_feat[(size_t)qi * DM + lane];
    const float qp = q_pos[(size_t)qi * DM + lane];
    qb[w][lane] = __float2bfloat16(qf + qp);
    for (int idx = tid; idx < 12 * 64; idx += 256)
        qb[4 + (idx >> 6)][idx & 63] = __float2bfloat16(0.f);
    if (tid < 8) refs[tid >> 1][tid & 1] = ref_pts[(size_t)(q0 + (tid >> 1)) * 2 + (tid & 1)];
    __syncthreads();

    // ---- phase B: [offs|aws] = q @ [Wo|Wa] + bias via MFMA (rows 0-3 valid) ----
    for (int nt = w; nt < 30; nt += 4) {
        f32x4 acc = {0.f, 0.f, 0.f, 0.f};
#pragma unroll
        for (int kc = 0; kc < 2; kc++) {
            const short8 a = *(const short8*)&qb[m16][kc * 32 + qd * 8];
            const short8 b = *(const short8*)(Woap + ((size_t)(nt * 2 + kc) * 64 + lane) * 8);
            acc = __builtin_amdgcn_mfma_f32_16x16x32_bf16(a, b, acc, 0, 0, 0);
        }
        if (qd == 0) {                       // rows 0..3 = queries 0..3
            const int n = nt * 16 + m16;
            if (n < 320) {
                const float bn = bo[n];
#pragma unroll
                for (int r = 0; r < 4; r++) offs[r][n] = acc[r] + bn;
            } else {
                const float bn = ba[n - 320];
#pragma unroll
                for (int r = 0; r < 4; r++) aws[r][n - 320] = acc[r] + bn;
            }
        }
    }
    __syncthreads();

    // ---- softmax per (query, head) over 20 ----
    if (tid < 32) {
        const int q = tid >> 3, h = tid & 7;
        float* p = &aws[q][h * 20];
        float mx = p[0];
        for (int j = 1; j < 20; j++) mx = fmaxf(mx, p[j]);
        float s = 0.f;
        for (int j = 0; j < 20; j++) { const float e = expf(p[j] - mx); p[j] = e; s += e; }
        const float inv = 1.f / s;
        for (int j = 0; j < 20; j++) p[j] *= inv;
    }
    __syncthreads();

    // ---- precompute per-corner descriptors (640 samples -> 2560 corners) ----
    for (int idx = tid; idx < 640; idx += 256) {
        const int q = idx / 160;
        const int m = idx - q * 160;          // h*20 + s
        const int h = m / 20;
        const int s = m - h * 20;             // l*4 + p
        const int l = s >> 2, p = s & 3;
        const int Wl = sz[l];
        const float Wf = (float)Wl;
        const int st = lsi[l];
        const int c = ((h * 5 + l) * 4 + p) * 2;
        const float ox = offs[q][c], oy = offs[q][c + 1];
        const float fx = (refs[q][0] + ox / Wf) * Wf - 0.5f;
        const float fy = (refs[q][1] + oy / Wf) * Wf - 0.5f;
        const float x0f = floorf(fx), y0f = floorf(fy);
        const float wx = fx - x0f, wy = fy - y0f;
        const int x0 = (int)x0f, y0 = (int)y0f;
        const float aV = aws[q][m];
        const bool xin0 = (x0 >= 0) & (x0 < Wl), xin1 = (x0 + 1 >= 0) & (x0 + 1 < Wl);
        const bool yin0 = (y0 >= 0) & (y0 < Wl), yin1 = (y0 + 1 >= 0) & (y0 + 1 < Wl);
        int2 d0, d1, d2, d3;
        d0.x = (xin0 && yin0) ? (st + y0 * Wl + x0) * 128 : 0;
        d0.y = __float_as_int((xin0 && yin0) ? (1.f - wx) * (1.f - wy) * aV : 0.f);
        d1.x = (xin1 && yin0) ? (st + y0 * Wl + x0 + 1) * 128 : 0;
        d1.y = __float_as_int((xin1 && yin0) ? wx * (1.f - wy) * aV : 0.f);
        d2.x = (xin0 && yin1) ? (st + (y0 + 1) * Wl + x0) * 128 : 0;
        d2.y = __float_as_int((xin0 && yin1) ? (1.f - wx) * wy * aV : 0.f);
        d3.x = (xin1 && yin1) ? (st + (y0 + 1) * Wl + x0 + 1) * 128 : 0;
        d3.y = __float_as_int((xin1 && yin1) ? wx * wy * aV : 0.f);
        int2* dst = &desc[(q * 8 + h) * 82 + s * 4];
        dst[0] = d0; dst[1] = d1; dst[2] = d2; dst[3] = d3;
    }
    __syncthreads();

    // ---- phase C: row-oriented gathers; lane = h*8 + j, 10 corners/lane ----
    {
        const int h = lane >> 3, j = lane & 7;
        const char* vb = (const char*)valp + h * 16;      // head h row segment
        float acc[8];
#pragma unroll
        for (int k = 0; k < 8; k++) acc[k] = 0.f;
        const int dbase = (w * 8 + h) * 82 + j;
#pragma unroll
        for (int t = 0; t < 10; t++) {
            const int2 d = desc[dbase + 8 * t];
            const uint4 row = *(const uint4*)(vb + d.x);
            const float wt = __int_as_float(d.y);
            acc[0] = fmaf(wt, lo16f(row.x), acc[0]);
            acc[1] = fmaf(wt, hi16f(row.x), acc[1]);
            acc[2] = fmaf(wt, lo16f(row.y), acc[2]);
            acc[3] = fmaf(wt, hi16f(row.y), acc[3]);
            acc[4] = fmaf(wt, lo16f(row.z), acc[4]);
            acc[5] = fmaf(wt, hi16f(row.z), acc[5]);
            acc[6] = fmaf(wt, lo16f(row.w), acc[6]);
            acc[7] = fmaf(wt, hi16f(row.w), acc[7]);
        }
#pragma unroll
        for (int o = 1; o <= 4; o <<= 1) {
#pragma unroll
            for (int k = 0; k < 8; k++) acc[k] += __shfl_xor(acc[k], o, 64);
        }
        if (j == 0) {
            float4 v0; v0.x = acc[0]; v0.y = acc[1]; v0.z = acc[2]; v0.w = acc[3];
            float4 v1; v1.x = acc[4]; v1.y = acc[5]; v1.z = acc[6]; v1.w = acc[7];
            *(float4*)&outv[w][h * 8] = v0;
            *(float4*)&outv[w][h * 8 + 4] = v1;
        }
    }
    // wave-local LDS write->read; no block barrier needed

    // ---- phase D: attn @ Wout + bout; residual; LN1; store x1 ----
    {
        float attn = bout[lane];
#pragma unroll 8
        for (int k = 0; k < DM; k++)
            attn = fmaf(outv[w][k], Wout[k * DM + lane], attn);
        const float xpre = qf + attn;
        float s = xpre, s2 = xpre * xpre;
#pragma unroll
        for (int o = 32; o >= 1; o >>= 1) {
            s += __shfl_xor(s, o, 64);
            s2 += __shfl_xor(s2, o, 64);
        }
        const float mean = s * (1.f / 64.f);
        const float var = s2 * (1.f / 64.f) - mean * mean;
        const float xn = (xpre - mean) * rsqrtf(var + 1e-5f);
        xout[(size_t)qi * DM + lane] = xn * g1[lane] + b1[lane];
    }
}

// ---- kernel 4: FFN via MFMA, 16 queries/block; in-place on io ----
__global__ void __launch_bounds__(256)
ffn_kernel(const __hip_bfloat16* __restrict__ W1p, const float* __restrict__ bff1,
           const __hip_bfloat16* __restrict__ W2p, const float* __restrict__ bff2,
           const float* __restrict__ g2, const float* __restrict__ b2,
           float* __restrict__ io) {
    __shared__ __align__(16) __hip_bfloat16 xb[16][72];
    __shared__ __align__(16) float xs[16][64];
    __shared__ __align__(16) __hip_bfloat16 hb[16][520];
    __shared__ __align__(16) float yr[16][64];

    const int tid = threadIdx.x;
    const int lane = tid & 63;
    const int w = tid >> 6;
    const int m16 = lane & 15, qd = lane >> 4;
    const int q0 = blockIdx.x * 16;

    {
        const int q = tid >> 4, i = tid & 15;
        const float4 v = *(const float4*)&io[(size_t)(q0 + q) * DM + i * 4];
        *(float4*)&xs[q][i * 4] = v;
        xb[q][i * 4 + 0] = __float2bfloat16(v.x);
        xb[q][i * 4 + 1] = __float2bfloat16(v.y);
        xb[q][i * 4 + 2] = __float2bfloat16(v.z);
        xb[q][i * 4 + 3] = __float2bfloat16(v.w);
    }
    __syncthreads();

    f32x4 yacc = {0.f, 0.f, 0.f, 0.f};
#pragma unroll
    for (int half = 0; half < 2; half++) {
#pragma unroll 2
        for (int ti = 0; ti < 8; ti++) {
            const int nt = half * 32 + w + ti * 4;
            f32x4 acc = {0.f, 0.f, 0.f, 0.f};
#pragma unroll
            for (int kc = 0; kc < 2; kc++) {
                const short8 a = *(const short8*)&xb[m16][kc * 32 + qd * 8];
                const short8 b = *(const short8*)(W1p + ((size_t)(nt * 2 + kc) * 64 + lane) * 8);
                acc = __builtin_amdgcn_mfma_f32_16x16x32_bf16(a, b, acc, 0, 0, 0);
            }
            const int ncol = (nt - half * 32) * 16 + m16;
            const float bn = bff1[nt * 16 + m16];
#pragma unroll
            for (int r = 0; r < 4; r++)
                hb[qd * 4 + r][ncol] = __float2bfloat16(fmaxf(acc[r] + bn, 0.f));
        }
        __syncthreads();
#pragma unroll 4
        for (int kc2 = 0; kc2 < 16; kc2++) {
            const short8 a = *(const short8*)&hb[m16][kc2 * 32 + qd * 8];
            const short8 b = *(const short8*)(W2p + ((size_t)(w * 32 + half * 16 + kc2) * 64 + lane) * 8);
            yacc = __builtin_amdgcn_mfma_f32_16x16x32_bf16(a, b, yacc, 0, 0, 0);
        }
        __syncthreads();
    }

    {
        const int n = w * 16 + m16;
        const float bn = bff2[n];
#pragma unroll
        for (int r = 0; r < 4; r++) {
            const int mm = qd * 4 + r;
            yr[mm][n] = yacc[r] + bn + xs[mm][n];
        }
    }
    __syncthreads();

    {
        const int q = tid >> 4, i = tid & 15;
        const float4 v = *(const float4*)&yr[q][i * 4];
        float s = v.x + v.y + v.z + v.w;
        float s2 = v.x * v.x + v.y * v.y + v.z * v.z + v.w * v.w;
#pragma unroll
        for (int o = 8; o >= 1; o >>= 1) { s += __shfl_xor(s, o, 64); s2 += __shfl_xor(s2, o, 64); }
        const float mean = s * (1.f / 64.f);
        const float var = s2 * (1.f / 64.f) - mean * mean;
        const float rstd = rsqrtf(var + 1e-5f);
        const float4 g = *(const float4*)&g2[i * 4];
        const float4 bb = *(const float4*)&b2[i * 4];
        float4 o;
        o.x = (v.x - mean) * rstd * g.x + bb.x;
        o.y = (v.y - mean) * rstd * g.y + bb.y;
        o.z = (v.z - mean) * rstd * g.z + bb.z;
        o.w = (v.w - mean) * rstd * g.w + bb.w;
        *(float4*)&io[(size_t)(q0 + q) * DM + i * 4] = o;
    }
}

extern "C" void kernel_launch(void* const* d_in, const int* in_sizes, int n_in,
                              void* d_out, int out_size, void* d_ws, size_t ws_size,
                              hipStream_t stream) {
    const int B0 = (in_sizes[4] >= 4096) ? 4 : 6;   // int side-inputs present -> 6
    const float* q_feat = (const float*)d_in[0];
    const float* dvf    = (const float*)d_in[1];
    const float* refp   = (const float*)d_in[2];
    const float* q_pos  = (const float*)d_in[3];
    const float* Wv   = (const float*)d_in[B0 + 0];
    const float* bv   = (const float*)d_in[B0 + 1];
    const float* Wo   = (const float*)d_in[B0 + 2];
    const float* bo   = (const float*)d_in[B0 + 3];
    const float* Wa   = (const float*)d_in[B0 + 4];
    const float* ba   = (const float*)d_in[B0 + 5];
    const float* Wout = (const float*)d_in[B0 + 6];
    const float* bout = (const float*)d_in[B0 + 7];
    const float* g1   = (const float*)d_in[B0 + 8];
    const float* b1   = (const float*)d_in[B0 + 9];
    const float* W1   = (const float*)d_in[B0 + 10];
    const float* bff1 = (const float*)d_in[B0 + 11];
    const float* W2   = (const float*)d_in[B0 + 12];
    const float* bff2 = (const float*)d_in[B0 + 13];
    const float* g2   = (const float*)d_in[B0 + 14];
    const float* b2   = (const float*)d_in[B0 + 15];
    float* out = (float*)d_out;

    const size_t val_elems = (size_t)LIN * DM;
    const size_t pack_elems = (size_t)(128 + 128 + 60) * 64 * 8;   // 161792 bf16
    const bool dbuf = ws_size >= (pack_elems + 2 * val_elems) * sizeof(__hip_bfloat16);

    __hip_bfloat16* W1p = (__hip_bfloat16*)d_ws;
    __hip_bfloat16* W2p = W1p + (size_t)128 * 64 * 8;
    __hip_bfloat16* Woap = W2p + (size_t)128 * 64 * 8;
    __hip_bfloat16* val0 = W1p + pack_elems;
    __hip_bfloat16* val1 = dbuf ? val0 + val_elems : val0;

    pack_kernel<<<79, 256, 0, stream>>>(W1, W2, Wo, Wa, W1p, W2p, Woap);

    if (dbuf) {
        // both batches in one launch each
        val_proj_kernel<<<(2 * LIN + 3) / 4, 256, 0, stream>>>(
            dvf, Wv, bv, val0, val1, 2 * LIN);
        attn4_kernel<<<(NB * NQ) / 4, 256, 0, stream>>>(
            q_feat, refp, q_pos, Woap, bo, ba, Wout, bout, g1, b1,
            val0, val1, 0, out);
    } else {
        for (int b = 0; b < NB; b++) {
            val_proj_kernel<<<(LIN + 3) / 4, 256, 0, stream>>>(
                dvf + (size_t)b * val_elems, Wv, bv, val0, val0, LIN);
            attn4_kernel<<<NQ / 4, 256, 0, stream>>>(
                q_feat, refp, q_pos, Woap, bo, ba, Wout, bout, g1, b1,
                val0, val0, b * NQ, out);
        }
    }
    ffn_kernel<<<(NB * NQ) / 16, 256, 0, stream>>>(W1p, bff1, W2p, bff2, g2, b2, out);
}

// Round 11
// 306.971 us; speedup vs baseline: 1.1046x; 1.1046x over previous
//
#include <hip/hip_runtime.h>
#include <hip/hip_bf16.h>

#define NB 2
#define NQ 20000
#define DM 64
#define NH 8
#define NL 5
#define NP 4
#define LIN 45109
#define FFN 1024

typedef __attribute__((ext_vector_type(8))) short short8;
typedef __attribute__((ext_vector_type(4))) float f32x4;

__device__ __forceinline__ float b2f(const __hip_bfloat16 h) { return __bfloat162float(h); }
__device__ __forceinline__ float lo16f(unsigned u) { return __uint_as_float(u << 16); }
__device__ __forceinline__ float hi16f(unsigned u) { return __uint_as_float(u & 0xffff0000u); }
__device__ __forceinline__ unsigned f2bf_bits(float x) {   // RNE round to bf16 bits
    unsigned u = __float_as_uint(x);
    return (u + 0x7FFFu + ((u >> 16) & 1u)) >> 16;
}

// ---- kernel 1: val[row,c] = (dvf[row,:] @ Wv + bv)[c]; handles 1 or 2 batches ----
__global__ void val_proj_kernel(const float* __restrict__ dvf,
                                const float* __restrict__ Wv,
                                const float* __restrict__ bv,
                                __hip_bfloat16* __restrict__ valA,
                                __hip_bfloat16* __restrict__ valB,
                                int rows) {
    const int lane = threadIdx.x & 63;
    const int row = blockIdx.x * 4 + (threadIdx.x >> 6);
    if (row >= rows) return;
    float mine = dvf[(size_t)row * DM + lane];
    float acc = bv[lane];
#pragma unroll 8
    for (int k = 0; k < DM; k++) {
        float vk = __shfl(mine, k, 64);
        acc = fmaf(vk, Wv[k * DM + lane], acc);
    }
    __hip_bfloat16* dst = (row < LIN) ? (valA + (size_t)row * DM)
                                      : (valB + (size_t)(row - LIN) * DM);
    dst[lane] = __float2bfloat16(acc);
}

// ---- kernel 2: pack W1/W2/[Wo|Wa] to bf16 MFMA B-fragment order ----
// B-frag 16x16x32: lane holds B[k=(lane>>4)*8+j][n=lane&15], j=0..7.
__global__ void pack_kernel(const float* __restrict__ W1, const float* __restrict__ W2,
                            const float* __restrict__ Wo, const float* __restrict__ Wa,
                            __hip_bfloat16* __restrict__ W1p, __hip_bfloat16* __restrict__ W2p,
                            __hip_bfloat16* __restrict__ Woap) {
    const int t = blockIdx.x * 256 + threadIdx.x;
    const int lane = t & 63;
    const int m = lane & 15, qd = lane >> 4;
    const int seg = t >> 6;
    if (seg < 128) {                  // W1 (64x1024): 64 ntiles x 2 kchunks
        const int nt = seg >> 1, kc = seg & 1;
        const int n = nt * 16 + m, kb = kc * 32 + qd * 8;
        __hip_bfloat16* dst = W1p + ((size_t)seg * 64 + lane) * 8;
#pragma unroll
        for (int j = 0; j < 8; j++) dst[j] = __float2bfloat16(W1[(size_t)(kb + j) * FFN + n]);
    } else if (seg < 256) {           // W2 (1024x64): 4 ntiles x 32 kchunks
        const int sl = seg - 128;
        const int nt = sl >> 5, kc = sl & 31;
        const int n = nt * 16 + m, kb = kc * 32 + qd * 8;
        __hip_bfloat16* dst = W2p + ((size_t)sl * 64 + lane) * 8;
#pragma unroll
        for (int j = 0; j < 8; j++) dst[j] = __float2bfloat16(W2[(size_t)(kb + j) * DM + n]);
    } else if (seg < 316) {           // [Wo|Wa] (64x480): 30 ntiles x 2 kchunks
        const int sl = seg - 256;
        const int nt = sl >> 1, kc = sl & 1;
        const int n = nt * 16 + m, kb = kc * 32 + qd * 8;
        __hip_bfloat16* dst = Woap + ((size_t)sl * 64 + lane) * 8;
#pragma unroll
        for (int j = 0; j < 8; j++) {
            const int k = kb + j;
            const float v = (n < 320) ? Wo[(size_t)k * 320 + n] : Wa[(size_t)k * 160 + (n - 320)];
            dst[j] = __float2bfloat16(v);
        }
    }
}

// ---- kernel 3: attn, 4 queries/block; B via MFMA; C via R9 descriptors (bf16 wts) ----
__global__ void __launch_bounds__(256)
attn4_kernel(const float* __restrict__ q_feat,
             const float* __restrict__ ref_pts,
             const float* __restrict__ q_pos,
             const __hip_bfloat16* __restrict__ Woap,
             const float* __restrict__ bo, const float* __restrict__ ba,
             const float* __restrict__ Wout, const float* __restrict__ bout,
             const float* __restrict__ g1, const float* __restrict__ b1,
             const __hip_bfloat16* __restrict__ valA,
             const __hip_bfloat16* __restrict__ valB,
             int qoff,
             float* __restrict__ xout) {
    __shared__ __align__(16) __hip_bfloat16 qb[16][72];   // A-frag; rows 4-15 zero
    __shared__ __align__(16) float offs[4][321];
    __shared__ __align__(16) float aws[4][161];
    __shared__ __align__(16) float refs[4][2];
    __shared__ __align__(16) int   dco[640][4];           // corner element offsets
    __shared__ __align__(16) uint2 dwp[640];              // 4 bf16 weights packed
    __shared__ __align__(16) float outv[4][64];

    const int tid = threadIdx.x;
    const int lane = tid & 63;
    const int w = tid >> 6;
    const int m16 = lane & 15, qd = lane >> 4;
    const int q0 = qoff + blockIdx.x * 4;                 // all 4 queries same batch
    const int qi = q0 + w;

    const int sz[NL]  = {184, 92, 46, 23, 12};
    const int lsi[NL] = {0, 33856, 42320, 44436, 44965};

    const __hip_bfloat16* valp = (q0 >= NQ) ? valB : valA;

    // ---- phase A: wave w owns query w ----
    const float qf = q_feat[(size_t)qi * DM + lane];
    const float qp = q_pos[(size_t)qi * DM + lane];
    qb[w][lane] = __float2bfloat16(qf + qp);
    for (int idx = tid; idx < 12 * 64; idx += 256)
        qb[4 + (idx >> 6)][idx & 63] = __float2bfloat16(0.f);
    if (tid < 8) refs[tid >> 1][tid & 1] = ref_pts[(size_t)(q0 + (tid >> 1)) * 2 + (tid & 1)];
    __syncthreads();

    // ---- phase B: [offs|aws] = q @ [Wo|Wa] + bias via MFMA (rows 0-3 valid) ----
    for (int nt = w; nt < 30; nt += 4) {
        f32x4 acc = {0.f, 0.f, 0.f, 0.f};
#pragma unroll
        for (int kc = 0; kc < 2; kc++) {
            const short8 a = *(const short8*)&qb[m16][kc * 32 + qd * 8];
            const short8 b = *(const short8*)(Woap + ((size_t)(nt * 2 + kc) * 64 + lane) * 8);
            acc = __builtin_amdgcn_mfma_f32_16x16x32_bf16(a, b, acc, 0, 0, 0);
        }
        if (qd == 0) {                       // rows 0..3 = queries 0..3
            const int n = nt * 16 + m16;
            if (n < 320) {
                const float bn = bo[n];
#pragma unroll
                for (int r = 0; r < 4; r++) offs[r][n] = acc[r] + bn;
            } else {
                const float bn = ba[n - 320];
#pragma unroll
                for (int r = 0; r < 4; r++) aws[r][n - 320] = acc[r] + bn;
            }
        }
    }
    __syncthreads();

    // ---- softmax per (query, head) over 20 ----
    if (tid < 32) {
        const int q = tid >> 3, h = tid & 7;
        float* p = &aws[q][h * 20];
        float mx = p[0];
        for (int j = 1; j < 20; j++) mx = fmaxf(mx, p[j]);
        float s = 0.f;
        for (int j = 0; j < 20; j++) { const float e = expf(p[j] - mx); p[j] = e; s += e; }
        const float inv = 1.f / s;
        for (int j = 0; j < 20; j++) p[j] *= inv;
    }
    __syncthreads();

    // ---- precompute sample descriptors: s = ((q*5+l)*4+p)*8 + h ----
    for (int s = tid; s < 640; s += 256) {
        const int h = s & 7;
        const int t2 = s >> 3;
        const int p = t2 & 3;
        const int t3 = t2 >> 2;           // q*5 + l
        const int l = t3 % 5;
        const int q = t3 / 5;
        const int Wl = sz[l];
        const float Wf = (float)Wl;
        const int st = lsi[l];
        const int c = ((h * 5 + l) * 4 + p) * 2;
        const float ox = offs[q][c], oy = offs[q][c + 1];
        const float fx = (refs[q][0] + ox / Wf) * Wf - 0.5f;
        const float fy = (refs[q][1] + oy / Wf) * Wf - 0.5f;
        const float x0f = floorf(fx), y0f = floorf(fy);
        const float wx = fx - x0f, wy = fy - y0f;
        const int x0 = (int)x0f, y0 = (int)y0f;
        const float aV = aws[q][h * 20 + l * 4 + p];
        const bool xin0 = (x0 >= 0) & (x0 < Wl), xin1 = (x0 + 1 >= 0) & (x0 + 1 < Wl);
        const bool yin0 = (y0 >= 0) & (y0 < Wl), yin1 = (y0 + 1 >= 0) & (y0 + 1 < Wl);
        int4 co;
        float w00 = 0.f, w10 = 0.f, w01 = 0.f, w11 = 0.f;
        co.x = (xin0 && yin0) ? (st + y0 * Wl + x0) * DM : 0;
        if (xin0 && yin0) w00 = (1.f - wx) * (1.f - wy) * aV;
        co.y = (xin1 && yin0) ? (st + y0 * Wl + x0 + 1) * DM : 0;
        if (xin1 && yin0) w10 = wx * (1.f - wy) * aV;
        co.z = (xin0 && yin1) ? (st + (y0 + 1) * Wl + x0) * DM : 0;
        if (xin0 && yin1) w01 = (1.f - wx) * wy * aV;
        co.w = (xin1 && yin1) ? (st + (y0 + 1) * Wl + x0 + 1) * DM : 0;
        if (xin1 && yin1) w11 = wx * wy * aV;
        *(int4*)dco[s] = co;
        uint2 dw;
        dw.x = f2bf_bits(w00) | (f2bf_bits(w10) << 16);
        dw.y = f2bf_bits(w01) | (f2bf_bits(w11) << 16);
        dwp[s] = dw;
    }
    __syncthreads();

    // ---- phase C: sampling, wave = query w; lane = h*8 + d (R9-validated form) ----
    {
        const int h = lane >> 3;
        const __hip_bfloat16* vbase = valp + lane;
        float acc = 0.f;
#pragma unroll
        for (int l = 0; l < NL; l++) {
#pragma unroll
            for (int p = 0; p < NP; p++) {
                const int idx = ((w * 5 + l) * 4 + p) * 8 + h;
                const int4 co = *(const int4*)dco[idx];
                const uint2 dw = dwp[idx];
                acc = fmaf(lo16f(dw.x), b2f(vbase[co.x]), acc);
                acc = fmaf(hi16f(dw.x), b2f(vbase[co.y]), acc);
                acc = fmaf(lo16f(dw.y), b2f(vbase[co.z]), acc);
                acc = fmaf(hi16f(dw.y), b2f(vbase[co.w]), acc);
            }
        }
        outv[w][lane] = acc;   // wave-local write, wave-local read below
    }

    // ---- phase D: attn @ Wout + bout; residual; LN1; store x1 ----
    {
        float attn = bout[lane];
#pragma unroll 8
        for (int k = 0; k < DM; k++)
            attn = fmaf(outv[w][k], Wout[k * DM + lane], attn);
        const float xpre = qf + attn;
        float s = xpre, s2 = xpre * xpre;
#pragma unroll
        for (int o = 32; o >= 1; o >>= 1) {
            s += __shfl_xor(s, o, 64);
            s2 += __shfl_xor(s2, o, 64);
        }
        const float mean = s * (1.f / 64.f);
        const float var = s2 * (1.f / 64.f) - mean * mean;
        const float xn = (xpre - mean) * rsqrtf(var + 1e-5f);
        xout[(size_t)qi * DM + lane] = xn * g1[lane] + b1[lane];
    }
}

// ---- kernel 4: FFN via MFMA, 16 queries/block; in-place on io ----
__global__ void __launch_bounds__(256)
ffn_kernel(const __hip_bfloat16* __restrict__ W1p, const float* __restrict__ bff1,
           const __hip_bfloat16* __restrict__ W2p, const float* __restrict__ bff2,
           const float* __restrict__ g2, const float* __restrict__ b2,
           float* __restrict__ io) {
    __shared__ __align__(16) __hip_bfloat16 xb[16][72];
    __shared__ __align__(16) float xs[16][64];
    __shared__ __align__(16) __hip_bfloat16 hb[16][520];
    __shared__ __align__(16) float yr[16][64];

    const int tid = threadIdx.x;
    const int lane = tid & 63;
    const int w = tid >> 6;
    const int m16 = lane & 15, qd = lane >> 4;
    const int q0 = blockIdx.x * 16;

    {
        const int q = tid >> 4, i = tid & 15;
        const float4 v = *(const float4*)&io[(size_t)(q0 + q) * DM + i * 4];
        *(float4*)&xs[q][i * 4] = v;
        xb[q][i * 4 + 0] = __float2bfloat16(v.x);
        xb[q][i * 4 + 1] = __float2bfloat16(v.y);
        xb[q][i * 4 + 2] = __float2bfloat16(v.z);
        xb[q][i * 4 + 3] = __float2bfloat16(v.w);
    }
    __syncthreads();

    f32x4 yacc = {0.f, 0.f, 0.f, 0.f};
#pragma unroll
    for (int half = 0; half < 2; half++) {
#pragma unroll 2
        for (int ti = 0; ti < 8; ti++) {
            const int nt = half * 32 + w + ti * 4;
            f32x4 acc = {0.f, 0.f, 0.f, 0.f};
#pragma unroll
            for (int kc = 0; kc < 2; kc++) {
                const short8 a = *(const short8*)&xb[m16][kc * 32 + qd * 8];
                const short8 b = *(const short8*)(W1p + ((size_t)(nt * 2 + kc) * 64 + lane) * 8);
                acc = __builtin_amdgcn_mfma_f32_16x16x32_bf16(a, b, acc, 0, 0, 0);
            }
            const int ncol = (nt - half * 32) * 16 + m16;
            const float bn = bff1[nt * 16 + m16];
#pragma unroll
            for (int r = 0; r < 4; r++)
                hb[qd * 4 + r][ncol] = __float2bfloat16(fmaxf(acc[r] + bn, 0.f));
        }
        __syncthreads();
#pragma unroll 4
        for (int kc2 = 0; kc2 < 16; kc2++) {
            const short8 a = *(const short8*)&hb[m16][kc2 * 32 + qd * 8];
            const short8 b = *(const short8*)(W2p + ((size_t)(w * 32 + half * 16 + kc2) * 64 + lane) * 8);
            yacc = __builtin_amdgcn_mfma_f32_16x16x32_bf16(a, b, yacc, 0, 0, 0);
        }
        __syncthreads();
    }

    {
        const int n = w * 16 + m16;
        const float bn = bff2[n];
#pragma unroll
        for (int r = 0; r < 4; r++) {
            const int mm = qd * 4 + r;
            yr[mm][n] = yacc[r] + bn + xs[mm][n];
        }
    }
    __syncthreads();

    {
        const int q = tid >> 4, i = tid & 15;
        const float4 v = *(const float4*)&yr[q][i * 4];
        float s = v.x + v.y + v.z + v.w;
        float s2 = v.x * v.x + v.y * v.y + v.z * v.z + v.w * v.w;
#pragma unroll
        for (int o = 8; o >= 1; o >>= 1) { s += __shfl_xor(s, o, 64); s2 += __shfl_xor(s2, o, 64); }
        const float mean = s * (1.f / 64.f);
        const float var = s2 * (1.f / 64.f) - mean * mean;
        const float rstd = rsqrtf(var + 1e-5f);
        const float4 g = *(const float4*)&g2[i * 4];
        const float4 bb = *(const float4*)&b2[i * 4];
        float4 o;
        o.x = (v.x - mean) * rstd * g.x + bb.x;
        o.y = (v.y - mean) * rstd * g.y + bb.y;
        o.z = (v.z - mean) * rstd * g.z + bb.z;
        o.w = (v.w - mean) * rstd * g.w + bb.w;
        *(float4*)&io[(size_t)(q0 + q) * DM + i * 4] = o;
    }
}

extern "C" void kernel_launch(void* const* d_in, const int* in_sizes, int n_in,
                              void* d_out, int out_size, void* d_ws, size_t ws_size,
                              hipStream_t stream) {
    const int B0 = (in_sizes[4] >= 4096) ? 4 : 6;   // int side-inputs present -> 6
    const float* q_feat = (const float*)d_in[0];
    const float* dvf    = (const float*)d_in[1];
    const float* refp   = (const float*)d_in[2];
    const float* q_pos  = (const float*)d_in[3];
    const float* Wv   = (const float*)d_in[B0 + 0];
    const float* bv   = (const float*)d_in[B0 + 1];
    const float* Wo   = (const float*)d_in[B0 + 2];
    const float* bo   = (const float*)d_in[B0 + 3];
    const float* Wa   = (const float*)d_in[B0 + 4];
    const float* ba   = (const float*)d_in[B0 + 5];
    const float* Wout = (const float*)d_in[B0 + 6];
    const float* bout = (const float*)d_in[B0 + 7];
    const float* g1   = (const float*)d_in[B0 + 8];
    const float* b1   = (const float*)d_in[B0 + 9];
    const float* W1   = (const float*)d_in[B0 + 10];
    const float* bff1 = (const float*)d_in[B0 + 11];
    const float* W2   = (const float*)d_in[B0 + 12];
    const float* bff2 = (const float*)d_in[B0 + 13];
    const float* g2   = (const float*)d_in[B0 + 14];
    const float* b2   = (const float*)d_in[B0 + 15];
    float* out = (float*)d_out;

    const size_t val_elems = (size_t)LIN * DM;
    const size_t pack_elems = (size_t)(128 + 128 + 60) * 64 * 8;   // 161792 bf16
    const bool dbuf = ws_size >= (pack_elems + 2 * val_elems) * sizeof(__hip_bfloat16);

    __hip_bfloat16* W1p = (__hip_bfloat16*)d_ws;
    __hip_bfloat16* W2p = W1p + (size_t)128 * 64 * 8;
    __hip_bfloat16* Woap = W2p + (size_t)128 * 64 * 8;
    __hip_bfloat16* val0 = W1p + pack_elems;
    __hip_bfloat16* val1 = dbuf ? val0 + val_elems : val0;

    pack_kernel<<<79, 256, 0, stream>>>(W1, W2, Wo, Wa, W1p, W2p, Woap);

    if (dbuf) {
        val_proj_kernel<<<(2 * LIN + 3) / 4, 256, 0, stream>>>(
            dvf, Wv, bv, val0, val1, 2 * LIN);
        attn4_kernel<<<(NB * NQ) / 4, 256, 0, stream>>>(
            q_feat, refp, q_pos, Woap, bo, ba, Wout, bout, g1, b1,
            val0, val1, 0, out);
    } else {
        for (int b = 0; b < NB; b++) {
            val_proj_kernel<<<(LIN + 3) / 4, 256, 0, stream>>>(
                dvf + (size_t)b * val_elems, Wv, bv, val0, val0, LIN);
            attn4_kernel<<<NQ / 4, 256, 0, stream>>>(
                q_feat, refp, q_pos, Woap, bo, ba, Wout, bout, g1, b1,
                val0, val0, b * NQ, out);
        }
    }
    ffn_kernel<<<(NB * NQ) / 16, 256, 0, stream>>>(W1p, bff1, W2p, bff2, g2, b2, out);
}

// Round 12
// 299.748 us; speedup vs baseline: 1.1312x; 1.0241x over previous
//
#include <hip/hip_runtime.h>
#include <hip/hip_bf16.h>

#define NB 2
#define NQ 20000
#define DM 64
#define NH 8
#define NL 5
#define NP 4
#define LIN 45109
#define FFN 1024

typedef __attribute__((ext_vector_type(8))) short short8;
typedef __attribute__((ext_vector_type(4))) float f32x4;

__device__ __forceinline__ float b2f(const __hip_bfloat16 h) { return __bfloat162float(h); }
__device__ __forceinline__ float lo16f(unsigned u) { return __uint_as_float(u << 16); }
__device__ __forceinline__ float hi16f(unsigned u) { return __uint_as_float(u & 0xffff0000u); }
__device__ __forceinline__ unsigned f2bf_bits(float x) {   // RNE round to bf16 bits
    unsigned u = __float_as_uint(x);
    return (u + 0x7FFFu + ((u >> 16) & 1u)) >> 16;
}

// ---- kernel 1: val[row,c] = (dvf[row,:] @ Wv + bv)[c]; handles 1 or 2 batches ----
__global__ void val_proj_kernel(const float* __restrict__ dvf,
                                const float* __restrict__ Wv,
                                const float* __restrict__ bv,
                                __hip_bfloat16* __restrict__ valA,
                                __hip_bfloat16* __restrict__ valB,
                                int rows) {
    const int lane = threadIdx.x & 63;
    const int row = blockIdx.x * 4 + (threadIdx.x >> 6);
    if (row >= rows) return;
    float mine = dvf[(size_t)row * DM + lane];
    float acc = bv[lane];
#pragma unroll 8
    for (int k = 0; k < DM; k++) {
        float vk = __shfl(mine, k, 64);
        acc = fmaf(vk, Wv[k * DM + lane], acc);
    }
    __hip_bfloat16* dst = (row < LIN) ? (valA + (size_t)row * DM)
                                      : (valB + (size_t)(row - LIN) * DM);
    dst[lane] = __float2bfloat16(acc);
}

// ---- kernel 2: pack W1/W2/[Wo|Wa] to bf16 MFMA B-fragment order ----
// B-frag 16x16x32: lane holds B[k=(lane>>4)*8+j][n=lane&15], j=0..7.
__global__ void pack_kernel(const float* __restrict__ W1, const float* __restrict__ W2,
                            const float* __restrict__ Wo, const float* __restrict__ Wa,
                            __hip_bfloat16* __restrict__ W1p, __hip_bfloat16* __restrict__ W2p,
                            __hip_bfloat16* __restrict__ Woap) {
    const int t = blockIdx.x * 256 + threadIdx.x;
    const int lane = t & 63;
    const int m = lane & 15, qd = lane >> 4;
    const int seg = t >> 6;
    if (seg < 128) {                  // W1 (64x1024): 64 ntiles x 2 kchunks
        const int nt = seg >> 1, kc = seg & 1;
        const int n = nt * 16 + m, kb = kc * 32 + qd * 8;
        __hip_bfloat16* dst = W1p + ((size_t)seg * 64 + lane) * 8;
#pragma unroll
        for (int j = 0; j < 8; j++) dst[j] = __float2bfloat16(W1[(size_t)(kb + j) * FFN + n]);
    } else if (seg < 256) {           // W2 (1024x64): 4 ntiles x 32 kchunks
        const int sl = seg - 128;
        const int nt = sl >> 5, kc = sl & 31;
        const int n = nt * 16 + m, kb = kc * 32 + qd * 8;
        __hip_bfloat16* dst = W2p + ((size_t)sl * 64 + lane) * 8;
#pragma unroll
        for (int j = 0; j < 8; j++) dst[j] = __float2bfloat16(W2[(size_t)(kb + j) * DM + n]);
    } else if (seg < 316) {           // [Wo|Wa] (64x480): 30 ntiles x 2 kchunks
        const int sl = seg - 256;
        const int nt = sl >> 1, kc = sl & 1;
        const int n = nt * 16 + m, kb = kc * 32 + qd * 8;
        __hip_bfloat16* dst = Woap + ((size_t)sl * 64 + lane) * 8;
#pragma unroll
        for (int j = 0; j < 8; j++) {
            const int k = kb + j;
            const float v = (n < 320) ? Wo[(size_t)k * 320 + n] : Wa[(size_t)k * 160 + (n - 320)];
            dst[j] = __float2bfloat16(v);
        }
    }
}

// ---- kernel 3: attn (R11-validated, unchanged) ----
__global__ void __launch_bounds__(256)
attn4_kernel(const float* __restrict__ q_feat,
             const float* __restrict__ ref_pts,
             const float* __restrict__ q_pos,
             const __hip_bfloat16* __restrict__ Woap,
             const float* __restrict__ bo, const float* __restrict__ ba,
             const float* __restrict__ Wout, const float* __restrict__ bout,
             const float* __restrict__ g1, const float* __restrict__ b1,
             const __hip_bfloat16* __restrict__ valA,
             const __hip_bfloat16* __restrict__ valB,
             int qoff,
             float* __restrict__ xout) {
    __shared__ __align__(16) __hip_bfloat16 qb[16][72];   // A-frag; rows 4-15 zero
    __shared__ __align__(16) float offs[4][321];
    __shared__ __align__(16) float aws[4][161];
    __shared__ __align__(16) float refs[4][2];
    __shared__ __align__(16) int   dco[640][4];           // corner element offsets
    __shared__ __align__(16) uint2 dwp[640];              // 4 bf16 weights packed
    __shared__ __align__(16) float outv[4][64];

    const int tid = threadIdx.x;
    const int lane = tid & 63;
    const int w = tid >> 6;
    const int m16 = lane & 15, qd = lane >> 4;
    const int q0 = qoff + blockIdx.x * 4;                 // all 4 queries same batch
    const int qi = q0 + w;

    const int sz[NL]  = {184, 92, 46, 23, 12};
    const int lsi[NL] = {0, 33856, 42320, 44436, 44965};

    const __hip_bfloat16* valp = (q0 >= NQ) ? valB : valA;

    // ---- phase A: wave w owns query w ----
    const float qf = q_feat[(size_t)qi * DM + lane];
    const float qp = q_pos[(size_t)qi * DM + lane];
    qb[w][lane] = __float2bfloat16(qf + qp);
    for (int idx = tid; idx < 12 * 64; idx += 256)
        qb[4 + (idx >> 6)][idx & 63] = __float2bfloat16(0.f);
    if (tid < 8) refs[tid >> 1][tid & 1] = ref_pts[(size_t)(q0 + (tid >> 1)) * 2 + (tid & 1)];
    __syncthreads();

    // ---- phase B: [offs|aws] = q @ [Wo|Wa] + bias via MFMA (rows 0-3 valid) ----
    for (int nt = w; nt < 30; nt += 4) {
        f32x4 acc = {0.f, 0.f, 0.f, 0.f};
#pragma unroll
        for (int kc = 0; kc < 2; kc++) {
            const short8 a = *(const short8*)&qb[m16][kc * 32 + qd * 8];
            const short8 b = *(const short8*)(Woap + ((size_t)(nt * 2 + kc) * 64 + lane) * 8);
            acc = __builtin_amdgcn_mfma_f32_16x16x32_bf16(a, b, acc, 0, 0, 0);
        }
        if (qd == 0) {                       // rows 0..3 = queries 0..3
            const int n = nt * 16 + m16;
            if (n < 320) {
                const float bn = bo[n];
#pragma unroll
                for (int r = 0; r < 4; r++) offs[r][n] = acc[r] + bn;
            } else {
                const float bn = ba[n - 320];
#pragma unroll
                for (int r = 0; r < 4; r++) aws[r][n - 320] = acc[r] + bn;
            }
        }
    }
    __syncthreads();

    // ---- softmax per (query, head) over 20 ----
    if (tid < 32) {
        const int q = tid >> 3, h = tid & 7;
        float* p = &aws[q][h * 20];
        float mx = p[0];
        for (int j = 1; j < 20; j++) mx = fmaxf(mx, p[j]);
        float s = 0.f;
        for (int j = 0; j < 20; j++) { const float e = expf(p[j] - mx); p[j] = e; s += e; }
        const float inv = 1.f / s;
        for (int j = 0; j < 20; j++) p[j] *= inv;
    }
    __syncthreads();

    // ---- precompute sample descriptors: s = ((q*5+l)*4+p)*8 + h ----
    for (int s = tid; s < 640; s += 256) {
        const int h = s & 7;
        const int t2 = s >> 3;
        const int p = t2 & 3;
        const int t3 = t2 >> 2;           // q*5 + l
        const int l = t3 % 5;
        const int q = t3 / 5;
        const int Wl = sz[l];
        const float Wf = (float)Wl;
        const int st = lsi[l];
        const int c = ((h * 5 + l) * 4 + p) * 2;
        const float ox = offs[q][c], oy = offs[q][c + 1];
        const float fx = (refs[q][0] + ox / Wf) * Wf - 0.5f;
        const float fy = (refs[q][1] + oy / Wf) * Wf - 0.5f;
        const float x0f = floorf(fx), y0f = floorf(fy);
        const float wx = fx - x0f, wy = fy - y0f;
        const int x0 = (int)x0f, y0 = (int)y0f;
        const float aV = aws[q][h * 20 + l * 4 + p];
        const bool xin0 = (x0 >= 0) & (x0 < Wl), xin1 = (x0 + 1 >= 0) & (x0 + 1 < Wl);
        const bool yin0 = (y0 >= 0) & (y0 < Wl), yin1 = (y0 + 1 >= 0) & (y0 + 1 < Wl);
        int4 co;
        float w00 = 0.f, w10 = 0.f, w01 = 0.f, w11 = 0.f;
        co.x = (xin0 && yin0) ? (st + y0 * Wl + x0) * DM : 0;
        if (xin0 && yin0) w00 = (1.f - wx) * (1.f - wy) * aV;
        co.y = (xin1 && yin0) ? (st + y0 * Wl + x0 + 1) * DM : 0;
        if (xin1 && yin0) w10 = wx * (1.f - wy) * aV;
        co.z = (xin0 && yin1) ? (st + (y0 + 1) * Wl + x0) * DM : 0;
        if (xin0 && yin1) w01 = (1.f - wx) * wy * aV;
        co.w = (xin1 && yin1) ? (st + (y0 + 1) * Wl + x0 + 1) * DM : 0;
        if (xin1 && yin1) w11 = wx * wy * aV;
        *(int4*)dco[s] = co;
        uint2 dw;
        dw.x = f2bf_bits(w00) | (f2bf_bits(w10) << 16);
        dw.y = f2bf_bits(w01) | (f2bf_bits(w11) << 16);
        dwp[s] = dw;
    }
    __syncthreads();

    // ---- phase C: sampling, wave = query w; lane = h*8 + d ----
    {
        const int h = lane >> 3;
        const __hip_bfloat16* vbase = valp + lane;
        float acc = 0.f;
#pragma unroll
        for (int l = 0; l < NL; l++) {
#pragma unroll
            for (int p = 0; p < NP; p++) {
                const int idx = ((w * 5 + l) * 4 + p) * 8 + h;
                const int4 co = *(const int4*)dco[idx];
                const uint2 dw = dwp[idx];
                acc = fmaf(lo16f(dw.x), b2f(vbase[co.x]), acc);
                acc = fmaf(hi16f(dw.x), b2f(vbase[co.y]), acc);
                acc = fmaf(lo16f(dw.y), b2f(vbase[co.z]), acc);
                acc = fmaf(hi16f(dw.y), b2f(vbase[co.w]), acc);
            }
        }
        outv[w][lane] = acc;   // wave-local write, wave-local read below
    }

    // ---- phase D: attn @ Wout + bout; residual; LN1; store x1 ----
    {
        float attn = bout[lane];
#pragma unroll 8
        for (int k = 0; k < DM; k++)
            attn = fmaf(outv[w][k], Wout[k * DM + lane], attn);
        const float xpre = qf + attn;
        float s = xpre, s2 = xpre * xpre;
#pragma unroll
        for (int o = 32; o >= 1; o >>= 1) {
            s += __shfl_xor(s, o, 64);
            s2 += __shfl_xor(s2, o, 64);
        }
        const float mean = s * (1.f / 64.f);
        const float var = s2 * (1.f / 64.f) - mean * mean;
        const float xn = (xpre - mean) * rsqrtf(var + 1e-5f);
        xout[(size_t)qi * DM + lane] = xn * g1[lane] + b1[lane];
    }
}

// ---- kernel 4: FFN via MFMA, 32 queries/block (2 M-tiles), hidden in 4 quarters ----
__global__ void __launch_bounds__(256)
ffn_kernel(const __hip_bfloat16* __restrict__ W1p, const float* __restrict__ bff1,
           const __hip_bfloat16* __restrict__ W2p, const float* __restrict__ bff2,
           const float* __restrict__ g2, const float* __restrict__ b2,
           float* __restrict__ io) {
    __shared__ __align__(16) __hip_bfloat16 xb[32][72];    // 4608 B
    __shared__ __align__(16) float xs[32][64];             // 8192 B
    __shared__ __align__(16) __hip_bfloat16 hb[32][264];   // 16896 B (256 cols + pad)
    __shared__ __align__(16) float yr[32][64];             // 8192 B

    const int tid = threadIdx.x;
    const int lane = tid & 63;
    const int w = tid >> 6;
    const int m16 = lane & 15, qd = lane >> 4;
    const int q0 = blockIdx.x * 32;

    // ---- load x1: thread t -> query t>>3, cols (t&7)*8 .. +7 ----
    {
        const int q = tid >> 3, i = tid & 7;
        const float4 v0 = *(const float4*)&io[(size_t)(q0 + q) * DM + i * 8];
        const float4 v1 = *(const float4*)&io[(size_t)(q0 + q) * DM + i * 8 + 4];
        *(float4*)&xs[q][i * 8] = v0;
        *(float4*)&xs[q][i * 8 + 4] = v1;
        __hip_bfloat16* xp = &xb[q][i * 8];
        xp[0] = __float2bfloat16(v0.x); xp[1] = __float2bfloat16(v0.y);
        xp[2] = __float2bfloat16(v0.z); xp[3] = __float2bfloat16(v0.w);
        xp[4] = __float2bfloat16(v1.x); xp[5] = __float2bfloat16(v1.y);
        xp[6] = __float2bfloat16(v1.z); xp[7] = __float2bfloat16(v1.w);
    }
    __syncthreads();

    f32x4 yacc[2];
    yacc[0] = (f32x4){0.f, 0.f, 0.f, 0.f};
    yacc[1] = (f32x4){0.f, 0.f, 0.f, 0.f};

#pragma unroll
    for (int qtr = 0; qtr < 4; qtr++) {
        // GEMM1 quarter: hidden cols [qtr*256, +256); wave w does ntiles qtr*16 + w + 4*ti
#pragma unroll
        for (int ti = 0; ti < 4; ti++) {
            const int nt = qtr * 16 + w + ti * 4;
            f32x4 acc[2];
            acc[0] = (f32x4){0.f, 0.f, 0.f, 0.f};
            acc[1] = (f32x4){0.f, 0.f, 0.f, 0.f};
#pragma unroll
            for (int kc = 0; kc < 2; kc++) {
                const short8 b = *(const short8*)(W1p + ((size_t)(nt * 2 + kc) * 64 + lane) * 8);
#pragma unroll
                for (int mt = 0; mt < 2; mt++) {
                    const short8 a = *(const short8*)&xb[mt * 16 + m16][kc * 32 + qd * 8];
                    acc[mt] = __builtin_amdgcn_mfma_f32_16x16x32_bf16(a, b, acc[mt], 0, 0, 0);
                }
            }
            const int ncol = (nt - qtr * 16) * 16 + m16;   // 0..255
            const float bn = bff1[nt * 16 + m16];
#pragma unroll
            for (int mt = 0; mt < 2; mt++)
#pragma unroll
                for (int r = 0; r < 4; r++)
                    hb[mt * 16 + qd * 4 + r][ncol] = __float2bfloat16(fmaxf(acc[mt][r] + bn, 0.f));
        }
        __syncthreads();
        // GEMM2 partial: wave w owns y-ntile w; this quarter's 8 kchunks
#pragma unroll
        for (int kc2 = 0; kc2 < 8; kc2++) {
            const short8 b = *(const short8*)(W2p + ((size_t)(w * 32 + qtr * 8 + kc2) * 64 + lane) * 8);
#pragma unroll
            for (int mt = 0; mt < 2; mt++) {
                const short8 a = *(const short8*)&hb[mt * 16 + m16][kc2 * 32 + qd * 8];
                yacc[mt] = __builtin_amdgcn_mfma_f32_16x16x32_bf16(a, b, yacc[mt], 0, 0, 0);
            }
        }
        __syncthreads();   // hb consumed before next quarter overwrites
    }

    // ---- Y + bff2 + x1 residual ----
    {
        const int n = w * 16 + m16;
        const float bn = bff2[n];
#pragma unroll
        for (int mt = 0; mt < 2; mt++)
#pragma unroll
            for (int r = 0; r < 4; r++) {
                const int mm = mt * 16 + qd * 4 + r;
                yr[mm][n] = yacc[mt][r] + bn + xs[mm][n];
            }
    }
    __syncthreads();

    // ---- LN2 + store: thread t -> query t>>3, cols (t&7)*8..+7; 8-lane reduce ----
    {
        const int q = tid >> 3, i = tid & 7;
        const float4 v0 = *(const float4*)&yr[q][i * 8];
        const float4 v1 = *(const float4*)&yr[q][i * 8 + 4];
        float s = v0.x + v0.y + v0.z + v0.w + v1.x + v1.y + v1.z + v1.w;
        float s2 = v0.x * v0.x + v0.y * v0.y + v0.z * v0.z + v0.w * v0.w
                 + v1.x * v1.x + v1.y * v1.y + v1.z * v1.z + v1.w * v1.w;
#pragma unroll
        for (int o = 4; o >= 1; o >>= 1) { s += __shfl_xor(s, o, 64); s2 += __shfl_xor(s2, o, 64); }
        const float mean = s * (1.f / 64.f);
        const float var = s2 * (1.f / 64.f) - mean * mean;
        const float rstd = rsqrtf(var + 1e-5f);
        const float4 ga = *(const float4*)&g2[i * 8];
        const float4 gb = *(const float4*)&g2[i * 8 + 4];
        const float4 ba4 = *(const float4*)&b2[i * 8];
        const float4 bb4 = *(const float4*)&b2[i * 8 + 4];
        float4 o0, o1;
        o0.x = (v0.x - mean) * rstd * ga.x + ba4.x;
        o0.y = (v0.y - mean) * rstd * ga.y + ba4.y;
        o0.z = (v0.z - mean) * rstd * ga.z + ba4.z;
        o0.w = (v0.w - mean) * rstd * ga.w + ba4.w;
        o1.x = (v1.x - mean) * rstd * gb.x + bb4.x;
        o1.y = (v1.y - mean) * rstd * gb.y + bb4.y;
        o1.z = (v1.z - mean) * rstd * gb.z + bb4.z;
        o1.w = (v1.w - mean) * rstd * gb.w + bb4.w;
        *(float4*)&io[(size_t)(q0 + q) * DM + i * 8] = o0;
        *(float4*)&io[(size_t)(q0 + q) * DM + i * 8 + 4] = o1;
    }
}

extern "C" void kernel_launch(void* const* d_in, const int* in_sizes, int n_in,
                              void* d_out, int out_size, void* d_ws, size_t ws_size,
                              hipStream_t stream) {
    const int B0 = (in_sizes[4] >= 4096) ? 4 : 6;   // int side-inputs present -> 6
    const float* q_feat = (const float*)d_in[0];
    const float* dvf    = (const float*)d_in[1];
    const float* refp   = (const float*)d_in[2];
    const float* q_pos  = (const float*)d_in[3];
    const float* Wv   = (const float*)d_in[B0 + 0];
    const float* bv   = (const float*)d_in[B0 + 1];
    const float* Wo   = (const float*)d_in[B0 + 2];
    const float* bo   = (const float*)d_in[B0 + 3];
    const float* Wa   = (const float*)d_in[B0 + 4];
    const float* ba   = (const float*)d_in[B0 + 5];
    const float* Wout = (const float*)d_in[B0 + 6];
    const float* bout = (const float*)d_in[B0 + 7];
    const float* g1   = (const float*)d_in[B0 + 8];
    const float* b1   = (const float*)d_in[B0 + 9];
    const float* W1   = (const float*)d_in[B0 + 10];
    const float* bff1 = (const float*)d_in[B0 + 11];
    const float* W2   = (const float*)d_in[B0 + 12];
    const float* bff2 = (const float*)d_in[B0 + 13];
    const float* g2   = (const float*)d_in[B0 + 14];
    const float* b2   = (const float*)d_in[B0 + 15];
    float* out = (float*)d_out;

    const size_t val_elems = (size_t)LIN * DM;
    const size_t pack_elems = (size_t)(128 + 128 + 60) * 64 * 8;   // 161792 bf16
    const bool dbuf = ws_size >= (pack_elems + 2 * val_elems) * sizeof(__hip_bfloat16);

    __hip_bfloat16* W1p = (__hip_bfloat16*)d_ws;
    __hip_bfloat16* W2p = W1p + (size_t)128 * 64 * 8;
    __hip_bfloat16* Woap = W2p + (size_t)128 * 64 * 8;
    __hip_bfloat16* val0 = W1p + pack_elems;
    __hip_bfloat16* val1 = dbuf ? val0 + val_elems : val0;

    pack_kernel<<<79, 256, 0, stream>>>(W1, W2, Wo, Wa, W1p, W2p, Woap);

    if (dbuf) {
        val_proj_kernel<<<(2 * LIN + 3) / 4, 256, 0, stream>>>(
            dvf, Wv, bv, val0, val1, 2 * LIN);
        attn4_kernel<<<(NB * NQ) / 4, 256, 0, stream>>>(
            q_feat, refp, q_pos, Woap, bo, ba, Wout, bout, g1, b1,
            val0, val1, 0, out);
    } else {
        for (int b = 0; b < NB; b++) {
            val_proj_kernel<<<(LIN + 3) / 4, 256, 0, stream>>>(
                dvf + (size_t)b * val_elems, Wv, bv, val0, val0, LIN);
            attn4_kernel<<<NQ / 4, 256, 0, stream>>>(
                q_feat, refp, q_pos, Woap, bo, ba, Wout, bout, g1, b1,
                val0, val0, b * NQ, out);
        }
    }
    ffn_kernel<<<(NB * NQ) / 32, 256, 0, stream>>>(W1p, bff1, W2p, bff2, g2, b2, out);
}

// Round 13
// 252.528 us; speedup vs baseline: 1.3427x; 1.1870x over previous
//
#include <hip/hip_runtime.h>
#include <hip/hip_bf16.h>

#define NB 2
#define NQ 20000
#define DM 64
#define NH 8
#define NL 5
#define NP 4
#define LIN 45109
#define FFN 1024

typedef __attribute__((ext_vector_type(8))) short short8;
typedef __attribute__((ext_vector_type(4))) float f32x4;

__device__ __forceinline__ float b2f(const __hip_bfloat16 h) { return __bfloat162float(h); }
__device__ __forceinline__ float lo16f(unsigned u) { return __uint_as_float(u << 16); }
__device__ __forceinline__ float hi16f(unsigned u) { return __uint_as_float(u & 0xffff0000u); }
__device__ __forceinline__ unsigned f2bf_bits(float x) {   // RNE round to bf16 bits
    unsigned u = __float_as_uint(x);
    return (u + 0x7FFFu + ((u >> 16) & 1u)) >> 16;
}

// ---- kernel 1: val = dvf @ Wv + bv via MFMA; 64 rows/block; 1 or 2 batches ----
__global__ void __launch_bounds__(256)
val_proj_kernel(const float* __restrict__ dvf,
                const float* __restrict__ Wv,
                const float* __restrict__ bv,
                __hip_bfloat16* __restrict__ valA,
                __hip_bfloat16* __restrict__ valB,
                int rows) {
    __shared__ __align__(16) __hip_bfloat16 wvp[8][64][8];  // B-frags: seg = nt*2+kc
    __shared__ __align__(16) __hip_bfloat16 ar[64][72];     // A rows, validated layout
    __shared__ __align__(16) float bvs[64];

    const int tid = threadIdx.x;
    const int lane = tid & 63;
    const int w = tid >> 6;
    const int m16 = lane & 15, qd = lane >> 4;
    const int row0 = blockIdx.x * 64;

    // pack Wv (64x64) into B-frag layout: B[k][n], k=(l>>4)*8+j + kc*32, n=nt*16+(l&15)
    for (int idx = tid; idx < 4096; idx += 256) {
        const int j = idx & 7;
        const int l = (idx >> 3) & 63;
        const int seg = idx >> 9;
        const int nt = seg >> 1, kc = seg & 1;
        const int n = nt * 16 + (l & 15);
        const int k = kc * 32 + (l >> 4) * 8 + j;
        wvp[seg][l][j] = __float2bfloat16(Wv[k * 64 + n]);
    }
    if (tid < 64) bvs[tid] = bv[tid];

    // wave w loads its 16 rows: lane -> row w*16+m16, cols qd*16..+15 (4x float4)
    {
        const int r = w * 16 + m16;
        const int grow = row0 + r;
        const int c0 = qd * 16;
        __hip_bfloat16* dst = &ar[r][c0];
        if (grow < rows) {
            const float4* src = (const float4*)&dvf[(size_t)grow * DM + c0];
#pragma unroll
            for (int t = 0; t < 4; t++) {
                const float4 v = src[t];
                dst[t * 4 + 0] = __float2bfloat16(v.x);
                dst[t * 4 + 1] = __float2bfloat16(v.y);
                dst[t * 4 + 2] = __float2bfloat16(v.z);
                dst[t * 4 + 3] = __float2bfloat16(v.w);
            }
        } else {
#pragma unroll
            for (int t = 0; t < 16; t++) dst[t] = __float2bfloat16(0.f);
        }
    }
    __syncthreads();

    // wave w computes M-tile w (rows w*16..+15): 4 ntiles x 2 kchunks
    f32x4 acc[4];
#pragma unroll
    for (int nt = 0; nt < 4; nt++) acc[nt] = (f32x4){0.f, 0.f, 0.f, 0.f};
#pragma unroll
    for (int kc = 0; kc < 2; kc++) {
        const short8 a = *(const short8*)&ar[w * 16 + m16][kc * 32 + qd * 8];
#pragma unroll
        for (int nt = 0; nt < 4; nt++) {
            const short8 b = *(const short8*)&wvp[nt * 2 + kc][lane][0];
            acc[nt] = __builtin_amdgcn_mfma_f32_16x16x32_bf16(a, b, acc[nt], 0, 0, 0);
        }
    }

    // store: D row = qd*4+r (voxel row), col = nt*16+m16 (channel)
#pragma unroll
    for (int r = 0; r < 4; r++) {
        const int gr = row0 + w * 16 + qd * 4 + r;
        if (gr < rows) {
            __hip_bfloat16* dst = (gr < LIN) ? (valA + (size_t)gr * DM)
                                             : (valB + (size_t)(gr - LIN) * DM);
#pragma unroll
            for (int nt = 0; nt < 4; nt++) {
                const int col = nt * 16 + m16;
                dst[col] = __float2bfloat16(acc[nt][r] + bvs[col]);
            }
        }
    }
}

// ---- kernel 2: pack W1/W2/[Wo|Wa] to bf16 MFMA B-fragment order ----
// B-frag 16x16x32: lane holds B[k=(lane>>4)*8+j][n=lane&15], j=0..7.
__global__ void pack_kernel(const float* __restrict__ W1, const float* __restrict__ W2,
                            const float* __restrict__ Wo, const float* __restrict__ Wa,
                            __hip_bfloat16* __restrict__ W1p, __hip_bfloat16* __restrict__ W2p,
                            __hip_bfloat16* __restrict__ Woap) {
    const int t = blockIdx.x * 256 + threadIdx.x;
    const int lane = t & 63;
    const int m = lane & 15, qd = lane >> 4;
    const int seg = t >> 6;
    if (seg < 128) {                  // W1 (64x1024): 64 ntiles x 2 kchunks
        const int nt = seg >> 1, kc = seg & 1;
        const int n = nt * 16 + m, kb = kc * 32 + qd * 8;
        __hip_bfloat16* dst = W1p + ((size_t)seg * 64 + lane) * 8;
#pragma unroll
        for (int j = 0; j < 8; j++) dst[j] = __float2bfloat16(W1[(size_t)(kb + j) * FFN + n]);
    } else if (seg < 256) {           // W2 (1024x64): 4 ntiles x 32 kchunks
        const int sl = seg - 128;
        const int nt = sl >> 5, kc = sl & 31;
        const int n = nt * 16 + m, kb = kc * 32 + qd * 8;
        __hip_bfloat16* dst = W2p + ((size_t)sl * 64 + lane) * 8;
#pragma unroll
        for (int j = 0; j < 8; j++) dst[j] = __float2bfloat16(W2[(size_t)(kb + j) * DM + n]);
    } else if (seg < 316) {           // [Wo|Wa] (64x480): 30 ntiles x 2 kchunks
        const int sl = seg - 256;
        const int nt = sl >> 1, kc = sl & 1;
        const int n = nt * 16 + m, kb = kc * 32 + qd * 8;
        __hip_bfloat16* dst = Woap + ((size_t)sl * 64 + lane) * 8;
#pragma unroll
        for (int j = 0; j < 8; j++) {
            const int k = kb + j;
            const float v = (n < 320) ? Wo[(size_t)k * 320 + n] : Wa[(size_t)k * 160 + (n - 320)];
            dst[j] = __float2bfloat16(v);
        }
    }
}

// ---- kernel 3: attn (R11-validated, unchanged) ----
__global__ void __launch_bounds__(256)
attn4_kernel(const float* __restrict__ q_feat,
             const float* __restrict__ ref_pts,
             const float* __restrict__ q_pos,
             const __hip_bfloat16* __restrict__ Woap,
             const float* __restrict__ bo, const float* __restrict__ ba,
             const float* __restrict__ Wout, const float* __restrict__ bout,
             const float* __restrict__ g1, const float* __restrict__ b1,
             const __hip_bfloat16* __restrict__ valA,
             const __hip_bfloat16* __restrict__ valB,
             int qoff,
             float* __restrict__ xout) {
    __shared__ __align__(16) __hip_bfloat16 qb[16][72];   // A-frag; rows 4-15 zero
    __shared__ __align__(16) float offs[4][321];
    __shared__ __align__(16) float aws[4][161];
    __shared__ __align__(16) float refs[4][2];
    __shared__ __align__(16) int   dco[640][4];           // corner element offsets
    __shared__ __align__(16) uint2 dwp[640];              // 4 bf16 weights packed
    __shared__ __align__(16) float outv[4][64];

    const int tid = threadIdx.x;
    const int lane = tid & 63;
    const int w = tid >> 6;
    const int m16 = lane & 15, qd = lane >> 4;
    const int q0 = qoff + blockIdx.x * 4;                 // all 4 queries same batch
    const int qi = q0 + w;

    const int sz[NL]  = {184, 92, 46, 23, 12};
    const int lsi[NL] = {0, 33856, 42320, 44436, 44965};

    const __hip_bfloat16* valp = (q0 >= NQ) ? valB : valA;

    // ---- phase A: wave w owns query w ----
    const float qf = q_feat[(size_t)qi * DM + lane];
    const float qp = q_pos[(size_t)qi * DM + lane];
    qb[w][lane] = __float2bfloat16(qf + qp);
    for (int idx = tid; idx < 12 * 64; idx += 256)
        qb[4 + (idx >> 6)][idx & 63] = __float2bfloat16(0.f);
    if (tid < 8) refs[tid >> 1][tid & 1] = ref_pts[(size_t)(q0 + (tid >> 1)) * 2 + (tid & 1)];
    __syncthreads();

    // ---- phase B: [offs|aws] = q @ [Wo|Wa] + bias via MFMA (rows 0-3 valid) ----
    for (int nt = w; nt < 30; nt += 4) {
        f32x4 acc = {0.f, 0.f, 0.f, 0.f};
#pragma unroll
        for (int kc = 0; kc < 2; kc++) {
            const short8 a = *(const short8*)&qb[m16][kc * 32 + qd * 8];
            const short8 b = *(const short8*)(Woap + ((size_t)(nt * 2 + kc) * 64 + lane) * 8);
            acc = __builtin_amdgcn_mfma_f32_16x16x32_bf16(a, b, acc, 0, 0, 0);
        }
        if (qd == 0) {                       // rows 0..3 = queries 0..3
            const int n = nt * 16 + m16;
            if (n < 320) {
                const float bn = bo[n];
#pragma unroll
                for (int r = 0; r < 4; r++) offs[r][n] = acc[r] + bn;
            } else {
                const float bn = ba[n - 320];
#pragma unroll
                for (int r = 0; r < 4; r++) aws[r][n - 320] = acc[r] + bn;
            }
        }
    }
    __syncthreads();

    // ---- softmax per (query, head) over 20 ----
    if (tid < 32) {
        const int q = tid >> 3, h = tid & 7;
        float* p = &aws[q][h * 20];
        float mx = p[0];
        for (int j = 1; j < 20; j++) mx = fmaxf(mx, p[j]);
        float s = 0.f;
        for (int j = 0; j < 20; j++) { const float e = expf(p[j] - mx); p[j] = e; s += e; }
        const float inv = 1.f / s;
        for (int j = 0; j < 20; j++) p[j] *= inv;
    }
    __syncthreads();

    // ---- precompute sample descriptors: s = ((q*5+l)*4+p)*8 + h ----
    for (int s = tid; s < 640; s += 256) {
        const int h = s & 7;
        const int t2 = s >> 3;
        const int p = t2 & 3;
        const int t3 = t2 >> 2;           // q*5 + l
        const int l = t3 % 5;
        const int q = t3 / 5;
        const int Wl = sz[l];
        const float Wf = (float)Wl;
        const int st = lsi[l];
        const int c = ((h * 5 + l) * 4 + p) * 2;
        const float ox = offs[q][c], oy = offs[q][c + 1];
        const float fx = (refs[q][0] + ox / Wf) * Wf - 0.5f;
        const float fy = (refs[q][1] + oy / Wf) * Wf - 0.5f;
        const float x0f = floorf(fx), y0f = floorf(fy);
        const float wx = fx - x0f, wy = fy - y0f;
        const int x0 = (int)x0f, y0 = (int)y0f;
        const float aV = aws[q][h * 20 + l * 4 + p];
        const bool xin0 = (x0 >= 0) & (x0 < Wl), xin1 = (x0 + 1 >= 0) & (x0 + 1 < Wl);
        const bool yin0 = (y0 >= 0) & (y0 < Wl), yin1 = (y0 + 1 >= 0) & (y0 + 1 < Wl);
        int4 co;
        float w00 = 0.f, w10 = 0.f, w01 = 0.f, w11 = 0.f;
        co.x = (xin0 && yin0) ? (st + y0 * Wl + x0) * DM : 0;
        if (xin0 && yin0) w00 = (1.f - wx) * (1.f - wy) * aV;
        co.y = (xin1 && yin0) ? (st + y0 * Wl + x0 + 1) * DM : 0;
        if (xin1 && yin0) w10 = wx * (1.f - wy) * aV;
        co.z = (xin0 && yin1) ? (st + (y0 + 1) * Wl + x0) * DM : 0;
        if (xin0 && yin1) w01 = (1.f - wx) * wy * aV;
        co.w = (xin1 && yin1) ? (st + (y0 + 1) * Wl + x0 + 1) * DM : 0;
        if (xin1 && yin1) w11 = wx * wy * aV;
        *(int4*)dco[s] = co;
        uint2 dw;
        dw.x = f2bf_bits(w00) | (f2bf_bits(w10) << 16);
        dw.y = f2bf_bits(w01) | (f2bf_bits(w11) << 16);
        dwp[s] = dw;
    }
    __syncthreads();

    // ---- phase C: sampling, wave = query w; lane = h*8 + d ----
    {
        const int h = lane >> 3;
        const __hip_bfloat16* vbase = valp + lane;
        float acc = 0.f;
#pragma unroll
        for (int l = 0; l < NL; l++) {
#pragma unroll
            for (int p = 0; p < NP; p++) {
                const int idx = ((w * 5 + l) * 4 + p) * 8 + h;
                const int4 co = *(const int4*)dco[idx];
                const uint2 dw = dwp[idx];
                acc = fmaf(lo16f(dw.x), b2f(vbase[co.x]), acc);
                acc = fmaf(hi16f(dw.x), b2f(vbase[co.y]), acc);
                acc = fmaf(lo16f(dw.y), b2f(vbase[co.z]), acc);
                acc = fmaf(hi16f(dw.y), b2f(vbase[co.w]), acc);
            }
        }
        outv[w][lane] = acc;   // wave-local write, wave-local read below
    }

    // ---- phase D: attn @ Wout + bout; residual; LN1; store x1 ----
    {
        float attn = bout[lane];
#pragma unroll 8
        for (int k = 0; k < DM; k++)
            attn = fmaf(outv[w][k], Wout[k * DM + lane], attn);
        const float xpre = qf + attn;
        float s = xpre, s2 = xpre * xpre;
#pragma unroll
        for (int o = 32; o >= 1; o >>= 1) {
            s += __shfl_xor(s, o, 64);
            s2 += __shfl_xor(s2, o, 64);
        }
        const float mean = s * (1.f / 64.f);
        const float var = s2 * (1.f / 64.f) - mean * mean;
        const float xn = (xpre - mean) * rsqrtf(var + 1e-5f);
        xout[(size_t)qi * DM + lane] = xn * g1[lane] + b1[lane];
    }
}

// ---- kernel 4: FFN via MFMA, 32 queries/block (2 M-tiles), hidden in 4 quarters ----
__global__ void __launch_bounds__(256)
ffn_kernel(const __hip_bfloat16* __restrict__ W1p, const float* __restrict__ bff1,
           const __hip_bfloat16* __restrict__ W2p, const float* __restrict__ bff2,
           const float* __restrict__ g2, const float* __restrict__ b2,
           float* __restrict__ io) {
    __shared__ __align__(16) __hip_bfloat16 xb[32][72];    // 4608 B
    __shared__ __align__(16) float xs[32][64];             // 8192 B
    __shared__ __align__(16) __hip_bfloat16 hb[32][264];   // 16896 B (256 cols + pad)
    __shared__ __align__(16) float yr[32][64];             // 8192 B

    const int tid = threadIdx.x;
    const int lane = tid & 63;
    const int w = tid >> 6;
    const int m16 = lane & 15, qd = lane >> 4;
    const int q0 = blockIdx.x * 32;

    // ---- load x1: thread t -> query t>>3, cols (t&7)*8 .. +7 ----
    {
        const int q = tid >> 3, i = tid & 7;
        const float4 v0 = *(const float4*)&io[(size_t)(q0 + q) * DM + i * 8];
        const float4 v1 = *(const float4*)&io[(size_t)(q0 + q) * DM + i * 8 + 4];
        *(float4*)&xs[q][i * 8] = v0;
        *(float4*)&xs[q][i * 8 + 4] = v1;
        __hip_bfloat16* xp = &xb[q][i * 8];
        xp[0] = __float2bfloat16(v0.x); xp[1] = __float2bfloat16(v0.y);
        xp[2] = __float2bfloat16(v0.z); xp[3] = __float2bfloat16(v0.w);
        xp[4] = __float2bfloat16(v1.x); xp[5] = __float2bfloat16(v1.y);
        xp[6] = __float2bfloat16(v1.z); xp[7] = __float2bfloat16(v1.w);
    }
    __syncthreads();

    f32x4 yacc[2];
    yacc[0] = (f32x4){0.f, 0.f, 0.f, 0.f};
    yacc[1] = (f32x4){0.f, 0.f, 0.f, 0.f};

#pragma unroll
    for (int qtr = 0; qtr < 4; qtr++) {
        // GEMM1 quarter: hidden cols [qtr*256, +256); wave w does ntiles qtr*16 + w + 4*ti
#pragma unroll
        for (int ti = 0; ti < 4; ti++) {
            const int nt = qtr * 16 + w + ti * 4;
            f32x4 acc[2];
            acc[0] = (f32x4){0.f, 0.f, 0.f, 0.f};
            acc[1] = (f32x4){0.f, 0.f, 0.f, 0.f};
#pragma unroll
            for (int kc = 0; kc < 2; kc++) {
                const short8 b = *(const short8*)(W1p + ((size_t)(nt * 2 + kc) * 64 + lane) * 8);
#pragma unroll
                for (int mt = 0; mt < 2; mt++) {
                    const short8 a = *(const short8*)&xb[mt * 16 + m16][kc * 32 + qd * 8];
                    acc[mt] = __builtin_amdgcn_mfma_f32_16x16x32_bf16(a, b, acc[mt], 0, 0, 0);
                }
            }
            const int ncol = (nt - qtr * 16) * 16 + m16;   // 0..255
            const float bn = bff1[nt * 16 + m16];
#pragma unroll
            for (int mt = 0; mt < 2; mt++)
#pragma unroll
                for (int r = 0; r < 4; r++)
                    hb[mt * 16 + qd * 4 + r][ncol] = __float2bfloat16(fmaxf(acc[mt][r] + bn, 0.f));
        }
        __syncthreads();
        // GEMM2 partial: wave w owns y-ntile w; this quarter's 8 kchunks
#pragma unroll
        for (int kc2 = 0; kc2 < 8; kc2++) {
            const short8 b = *(const short8*)(W2p + ((size_t)(w * 32 + qtr * 8 + kc2) * 64 + lane) * 8);
#pragma unroll
            for (int mt = 0; mt < 2; mt++) {
                const short8 a = *(const short8*)&hb[mt * 16 + m16][kc2 * 32 + qd * 8];
                yacc[mt] = __builtin_amdgcn_mfma_f32_16x16x32_bf16(a, b, yacc[mt], 0, 0, 0);
            }
        }
        __syncthreads();   // hb consumed before next quarter overwrites
    }

    // ---- Y + bff2 + x1 residual ----
    {
        const int n = w * 16 + m16;
        const float bn = bff2[n];
#pragma unroll
        for (int mt = 0; mt < 2; mt++)
#pragma unroll
            for (int r = 0; r < 4; r++) {
                const int mm = mt * 16 + qd * 4 + r;
                yr[mm][n] = yacc[mt][r] + bn + xs[mm][n];
            }
    }
    __syncthreads();

    // ---- LN2 + store: thread t -> query t>>3, cols (t&7)*8..+7; 8-lane reduce ----
    {
        const int q = tid >> 3, i = tid & 7;
        const float4 v0 = *(const float4*)&yr[q][i * 8];
        const float4 v1 = *(const float4*)&yr[q][i * 8 + 4];
        float s = v0.x + v0.y + v0.z + v0.w + v1.x + v1.y + v1.z + v1.w;
        float s2 = v0.x * v0.x + v0.y * v0.y + v0.z * v0.z + v0.w * v0.w
                 + v1.x * v1.x + v1.y * v1.y + v1.z * v1.z + v1.w * v1.w;
#pragma unroll
        for (int o = 4; o >= 1; o >>= 1) { s += __shfl_xor(s, o, 64); s2 += __shfl_xor(s2, o, 64); }
        const float mean = s * (1.f / 64.f);
        const float var = s2 * (1.f / 64.f) - mean * mean;
        const float rstd = rsqrtf(var + 1e-5f);
        const float4 ga = *(const float4*)&g2[i * 8];
        const float4 gb = *(const float4*)&g2[i * 8 + 4];
        const float4 ba4 = *(const float4*)&b2[i * 8];
        const float4 bb4 = *(const float4*)&b2[i * 8 + 4];
        float4 o0, o1;
        o0.x = (v0.x - mean) * rstd * ga.x + ba4.x;
        o0.y = (v0.y - mean) * rstd * ga.y + ba4.y;
        o0.z = (v0.z - mean) * rstd * ga.z + ba4.z;
        o0.w = (v0.w - mean) * rstd * ga.w + ba4.w;
        o1.x = (v1.x - mean) * rstd * gb.x + bb4.x;
        o1.y = (v1.y - mean) * rstd * gb.y + bb4.y;
        o1.z = (v1.z - mean) * rstd * gb.z + bb4.z;
        o1.w = (v1.w - mean) * rstd * gb.w + bb4.w;
        *(float4*)&io[(size_t)(q0 + q) * DM + i * 8] = o0;
        *(float4*)&io[(size_t)(q0 + q) * DM + i * 8 + 4] = o1;
    }
}

extern "C" void kernel_launch(void* const* d_in, const int* in_sizes, int n_in,
                              void* d_out, int out_size, void* d_ws, size_t ws_size,
                              hipStream_t stream) {
    const int B0 = (in_sizes[4] >= 4096) ? 4 : 6;   // int side-inputs present -> 6
    const float* q_feat = (const float*)d_in[0];
    const float* dvf    = (const float*)d_in[1];
    const float* refp   = (const float*)d_in[2];
    const float* q_pos  = (const float*)d_in[3];
    const float* Wv   = (const float*)d_in[B0 + 0];
    const float* bv   = (const float*)d_in[B0 + 1];
    const float* Wo   = (const float*)d_in[B0 + 2];
    const float* bo   = (const float*)d_in[B0 + 3];
    const float* Wa   = (const float*)d_in[B0 + 4];
    const float* ba   = (const float*)d_in[B0 + 5];
    const float* Wout = (const float*)d_in[B0 + 6];
    const float* bout = (const float*)d_in[B0 + 7];
    const float* g1   = (const float*)d_in[B0 + 8];
    const float* b1   = (const float*)d_in[B0 + 9];
    const float* W1   = (const float*)d_in[B0 + 10];
    const float* bff1 = (const float*)d_in[B0 + 11];
    const float* W2   = (const float*)d_in[B0 + 12];
    const float* bff2 = (const float*)d_in[B0 + 13];
    const float* g2   = (const float*)d_in[B0 + 14];
    const float* b2   = (const float*)d_in[B0 + 15];
    float* out = (float*)d_out;

    const size_t val_elems = (size_t)LIN * DM;
    const size_t pack_elems = (size_t)(128 + 128 + 60) * 64 * 8;   // 161792 bf16
    const bool dbuf = ws_size >= (pack_elems + 2 * val_elems) * sizeof(__hip_bfloat16);

    __hip_bfloat16* W1p = (__hip_bfloat16*)d_ws;
    __hip_bfloat16* W2p = W1p + (size_t)128 * 64 * 8;
    __hip_bfloat16* Woap = W2p + (size_t)128 * 64 * 8;
    __hip_bfloat16* val0 = W1p + pack_elems;
    __hip_bfloat16* val1 = dbuf ? val0 + val_elems : val0;

    pack_kernel<<<79, 256, 0, stream>>>(W1, W2, Wo, Wa, W1p, W2p, Woap);

    if (dbuf) {
        val_proj_kernel<<<(2 * LIN + 63) / 64, 256, 0, stream>>>(
            dvf, Wv, bv, val0, val1, 2 * LIN);
        attn4_kernel<<<(NB * NQ) / 4, 256, 0, stream>>>(
            q_feat, refp, q_pos, Woap, bo, ba, Wout, bout, g1, b1,
            val0, val1, 0, out);
    } else {
        for (int b = 0; b < NB; b++) {
            val_proj_kernel<<<(LIN + 63) / 64, 256, 0, stream>>>(
                dvf + (size_t)b * val_elems, Wv, bv, val0, val0, LIN);
            attn4_kernel<<<NQ / 4, 256, 0, stream>>>(
                q_feat, refp, q_pos, Woap, bo, ba, Wout, bout, g1, b1,
                val0, val0, b * NQ, out);
        }
    }
    ffn_kernel<<<(NB * NQ) / 32, 256, 0, stream>>>(W1p, bff1, W2p, bff2, g2, b2, out);
}

// Round 14
// 242.394 us; speedup vs baseline: 1.3989x; 1.0418x over previous
//
#include <hip/hip_runtime.h>
#include <hip/hip_bf16.h>

#define NB 2
#define NQ 20000
#define DM 64
#define NH 8
#define NL 5
#define NP 4
#define LIN 45109
#define FFN 1024

typedef __attribute__((ext_vector_type(8))) short short8;
typedef __attribute__((ext_vector_type(4))) float f32x4;

__device__ __forceinline__ float b2f(const __hip_bfloat16 h) { return __bfloat162float(h); }
__device__ __forceinline__ float lo16f(unsigned u) { return __uint_as_float(u << 16); }
__device__ __forceinline__ float hi16f(unsigned u) { return __uint_as_float(u & 0xffff0000u); }
__device__ __forceinline__ unsigned f2bf_bits(float x) {   // RNE round to bf16 bits
    unsigned u = __float_as_uint(x);
    return (u + 0x7FFFu + ((u >> 16) & 1u)) >> 16;
}

// ---- kernel 1: val = dvf @ Wv + bv via MFMA; 64 rows/block; 1 or 2 batches ----
__global__ void __launch_bounds__(256)
val_proj_kernel(const float* __restrict__ dvf,
                const float* __restrict__ Wv,
                const float* __restrict__ bv,
                __hip_bfloat16* __restrict__ valA,
                __hip_bfloat16* __restrict__ valB,
                int rows) {
    __shared__ __align__(16) __hip_bfloat16 wvp[8][64][8];  // B-frags: seg = nt*2+kc
    __shared__ __align__(16) __hip_bfloat16 ar[64][72];     // A rows, validated layout
    __shared__ __align__(16) float bvs[64];

    const int tid = threadIdx.x;
    const int lane = tid & 63;
    const int w = tid >> 6;
    const int m16 = lane & 15, qd = lane >> 4;
    const int row0 = blockIdx.x * 64;

    // pack Wv (64x64) into B-frag layout: B[k][n], k=(l>>4)*8+j + kc*32, n=nt*16+(l&15)
    for (int idx = tid; idx < 4096; idx += 256) {
        const int j = idx & 7;
        const int l = (idx >> 3) & 63;
        const int seg = idx >> 9;
        const int nt = seg >> 1, kc = seg & 1;
        const int n = nt * 16 + (l & 15);
        const int k = kc * 32 + (l >> 4) * 8 + j;
        wvp[seg][l][j] = __float2bfloat16(Wv[k * 64 + n]);
    }
    if (tid < 64) bvs[tid] = bv[tid];

    // wave w loads its 16 rows: lane -> row w*16+m16, cols qd*16..+15 (4x float4)
    {
        const int r = w * 16 + m16;
        const int grow = row0 + r;
        const int c0 = qd * 16;
        __hip_bfloat16* dst = &ar[r][c0];
        if (grow < rows) {
            const float4* src = (const float4*)&dvf[(size_t)grow * DM + c0];
#pragma unroll
            for (int t = 0; t < 4; t++) {
                const float4 v = src[t];
                dst[t * 4 + 0] = __float2bfloat16(v.x);
                dst[t * 4 + 1] = __float2bfloat16(v.y);
                dst[t * 4 + 2] = __float2bfloat16(v.z);
                dst[t * 4 + 3] = __float2bfloat16(v.w);
            }
        } else {
#pragma unroll
            for (int t = 0; t < 16; t++) dst[t] = __float2bfloat16(0.f);
        }
    }
    __syncthreads();

    // wave w computes M-tile w (rows w*16..+15): 4 ntiles x 2 kchunks
    f32x4 acc[4];
#pragma unroll
    for (int nt = 0; nt < 4; nt++) acc[nt] = (f32x4){0.f, 0.f, 0.f, 0.f};
#pragma unroll
    for (int kc = 0; kc < 2; kc++) {
        const short8 a = *(const short8*)&ar[w * 16 + m16][kc * 32 + qd * 8];
#pragma unroll
        for (int nt = 0; nt < 4; nt++) {
            const short8 b = *(const short8*)&wvp[nt * 2 + kc][lane][0];
            acc[nt] = __builtin_amdgcn_mfma_f32_16x16x32_bf16(a, b, acc[nt], 0, 0, 0);
        }
    }

    // store: D row = qd*4+r (voxel row), col = nt*16+m16 (channel)
#pragma unroll
    for (int r = 0; r < 4; r++) {
        const int gr = row0 + w * 16 + qd * 4 + r;
        if (gr < rows) {
            __hip_bfloat16* dst = (gr < LIN) ? (valA + (size_t)gr * DM)
                                             : (valB + (size_t)(gr - LIN) * DM);
#pragma unroll
            for (int nt = 0; nt < 4; nt++) {
                const int col = nt * 16 + m16;
                dst[col] = __float2bfloat16(acc[nt][r] + bvs[col]);
            }
        }
    }
}

// ---- kernel 2: pack W1/W2/[Wo|Wa]/Wout to bf16 MFMA B-fragment order ----
// B-frag 16x16x32: lane holds B[k=(lane>>4)*8+j][n=lane&15], j=0..7.
__global__ void pack_kernel(const float* __restrict__ W1, const float* __restrict__ W2,
                            const float* __restrict__ Wo, const float* __restrict__ Wa,
                            const float* __restrict__ Wout,
                            __hip_bfloat16* __restrict__ W1p, __hip_bfloat16* __restrict__ W2p,
                            __hip_bfloat16* __restrict__ Woap, __hip_bfloat16* __restrict__ Woutp) {
    const int t = blockIdx.x * 256 + threadIdx.x;
    const int lane = t & 63;
    const int m = lane & 15, qd = lane >> 4;
    const int seg = t >> 6;
    if (seg < 128) {                  // W1 (64x1024): 64 ntiles x 2 kchunks
        const int nt = seg >> 1, kc = seg & 1;
        const int n = nt * 16 + m, kb = kc * 32 + qd * 8;
        __hip_bfloat16* dst = W1p + ((size_t)seg * 64 + lane) * 8;
#pragma unroll
        for (int j = 0; j < 8; j++) dst[j] = __float2bfloat16(W1[(size_t)(kb + j) * FFN + n]);
    } else if (seg < 256) {           // W2 (1024x64): 4 ntiles x 32 kchunks
        const int sl = seg - 128;
        const int nt = sl >> 5, kc = sl & 31;
        const int n = nt * 16 + m, kb = kc * 32 + qd * 8;
        __hip_bfloat16* dst = W2p + ((size_t)sl * 64 + lane) * 8;
#pragma unroll
        for (int j = 0; j < 8; j++) dst[j] = __float2bfloat16(W2[(size_t)(kb + j) * DM + n]);
    } else if (seg < 316) {           // [Wo|Wa] (64x480): 30 ntiles x 2 kchunks
        const int sl = seg - 256;
        const int nt = sl >> 1, kc = sl & 1;
        const int n = nt * 16 + m, kb = kc * 32 + qd * 8;
        __hip_bfloat16* dst = Woap + ((size_t)sl * 64 + lane) * 8;
#pragma unroll
        for (int j = 0; j < 8; j++) {
            const int k = kb + j;
            const float v = (n < 320) ? Wo[(size_t)k * 320 + n] : Wa[(size_t)k * 160 + (n - 320)];
            dst[j] = __float2bfloat16(v);
        }
    } else if (seg < 324) {           // Wout (64x64): 4 ntiles x 2 kchunks (R8-validated)
        const int sl = seg - 316;
        const int nt = sl >> 1, kc = sl & 1;
        const int n = nt * 16 + m, kb = kc * 32 + qd * 8;
        __hip_bfloat16* dst = Woutp + ((size_t)sl * 64 + lane) * 8;
#pragma unroll
        for (int j = 0; j < 8; j++) dst[j] = __float2bfloat16(Wout[(size_t)(kb + j) * DM + n]);
    }
}

// ---- kernel 3: attn, 4 queries/block; B and D via MFMA; C via R11 descriptors ----
__global__ void __launch_bounds__(256)
attn4_kernel(const float* __restrict__ q_feat,
             const float* __restrict__ ref_pts,
             const float* __restrict__ q_pos,
             const __hip_bfloat16* __restrict__ Woap,
             const float* __restrict__ bo, const float* __restrict__ ba,
             const __hip_bfloat16* __restrict__ Woutp, const float* __restrict__ bout,
             const float* __restrict__ g1, const float* __restrict__ b1,
             const __hip_bfloat16* __restrict__ valA,
             const __hip_bfloat16* __restrict__ valB,
             int qoff,
             float* __restrict__ xout) {
    __shared__ __align__(16) __hip_bfloat16 qb[16][72];   // A-frag; rows 4-15 zero
    __shared__ __align__(16) float offs[4][321];
    __shared__ __align__(16) float aws[4][161];
    __shared__ __align__(16) float refs[4][2];
    __shared__ __align__(16) int   dco[640][4];           // corner element offsets
    __shared__ __align__(16) uint2 dwp[640];              // 4 bf16 weights packed
    __shared__ __align__(16) float xs4[4][64];            // phase-D output (pre-LN)

    const int tid = threadIdx.x;
    const int lane = tid & 63;
    const int w = tid >> 6;
    const int m16 = lane & 15, qd = lane >> 4;
    const int q0 = qoff + blockIdx.x * 4;                 // all 4 queries same batch
    const int qi = q0 + w;

    const int sz[NL]  = {184, 92, 46, 23, 12};
    const int lsi[NL] = {0, 33856, 42320, 44436, 44965};

    const __hip_bfloat16* valp = (q0 >= NQ) ? valB : valA;

    // ---- phase A: wave w owns query w ----
    const float qf = q_feat[(size_t)qi * DM + lane];
    const float qp = q_pos[(size_t)qi * DM + lane];
    qb[w][lane] = __float2bfloat16(qf + qp);
    for (int idx = tid; idx < 12 * 64; idx += 256)
        qb[4 + (idx >> 6)][idx & 63] = __float2bfloat16(0.f);
    if (tid < 8) refs[tid >> 1][tid & 1] = ref_pts[(size_t)(q0 + (tid >> 1)) * 2 + (tid & 1)];
    __syncthreads();

    // ---- phase B: [offs|aws] = q @ [Wo|Wa] + bias via MFMA (rows 0-3 valid) ----
    for (int nt = w; nt < 30; nt += 4) {
        f32x4 acc = {0.f, 0.f, 0.f, 0.f};
#pragma unroll
        for (int kc = 0; kc < 2; kc++) {
            const short8 a = *(const short8*)&qb[m16][kc * 32 + qd * 8];
            const short8 b = *(const short8*)(Woap + ((size_t)(nt * 2 + kc) * 64 + lane) * 8);
            acc = __builtin_amdgcn_mfma_f32_16x16x32_bf16(a, b, acc, 0, 0, 0);
        }
        if (qd == 0) {                       // rows 0..3 = queries 0..3
            const int n = nt * 16 + m16;
            if (n < 320) {
                const float bn = bo[n];
#pragma unroll
                for (int r = 0; r < 4; r++) offs[r][n] = acc[r] + bn;
            } else {
                const float bn = ba[n - 320];
#pragma unroll
                for (int r = 0; r < 4; r++) aws[r][n - 320] = acc[r] + bn;
            }
        }
    }
    __syncthreads();

    // ---- softmax per (query, head) over 20 ----
    if (tid < 32) {
        const int q = tid >> 3, h = tid & 7;
        float* p = &aws[q][h * 20];
        float mx = p[0];
        for (int j = 1; j < 20; j++) mx = fmaxf(mx, p[j]);
        float s = 0.f;
        for (int j = 0; j < 20; j++) { const float e = expf(p[j] - mx); p[j] = e; s += e; }
        const float inv = 1.f / s;
        for (int j = 0; j < 20; j++) p[j] *= inv;
    }
    __syncthreads();

    // ---- precompute sample descriptors: s = ((q*5+l)*4+p)*8 + h ----
    for (int s = tid; s < 640; s += 256) {
        const int h = s & 7;
        const int t2 = s >> 3;
        const int p = t2 & 3;
        const int t3 = t2 >> 2;           // q*5 + l
        const int l = t3 % 5;
        const int q = t3 / 5;
        const int Wl = sz[l];
        const float Wf = (float)Wl;
        const int st = lsi[l];
        const int c = ((h * 5 + l) * 4 + p) * 2;
        const float ox = offs[q][c], oy = offs[q][c + 1];
        const float fx = (refs[q][0] + ox / Wf) * Wf - 0.5f;
        const float fy = (refs[q][1] + oy / Wf) * Wf - 0.5f;
        const float x0f = floorf(fx), y0f = floorf(fy);
        const float wx = fx - x0f, wy = fy - y0f;
        const int x0 = (int)x0f, y0 = (int)y0f;
        const float aV = aws[q][h * 20 + l * 4 + p];
        const bool xin0 = (x0 >= 0) & (x0 < Wl), xin1 = (x0 + 1 >= 0) & (x0 + 1 < Wl);
        const bool yin0 = (y0 >= 0) & (y0 < Wl), yin1 = (y0 + 1 >= 0) & (y0 + 1 < Wl);
        int4 co;
        float w00 = 0.f, w10 = 0.f, w01 = 0.f, w11 = 0.f;
        co.x = (xin0 && yin0) ? (st + y0 * Wl + x0) * DM : 0;
        if (xin0 && yin0) w00 = (1.f - wx) * (1.f - wy) * aV;
        co.y = (xin1 && yin0) ? (st + y0 * Wl + x0 + 1) * DM : 0;
        if (xin1 && yin0) w10 = wx * (1.f - wy) * aV;
        co.z = (xin0 && yin1) ? (st + (y0 + 1) * Wl + x0) * DM : 0;
        if (xin0 && yin1) w01 = (1.f - wx) * wy * aV;
        co.w = (xin1 && yin1) ? (st + (y0 + 1) * Wl + x0 + 1) * DM : 0;
        if (xin1 && yin1) w11 = wx * wy * aV;
        *(int4*)dco[s] = co;
        uint2 dw;
        dw.x = f2bf_bits(w00) | (f2bf_bits(w10) << 16);
        dw.y = f2bf_bits(w01) | (f2bf_bits(w11) << 16);
        dwp[s] = dw;
    }
    __syncthreads();

    // ---- phase C: sampling, wave = query w; lane = h*8 + d; result -> qb[w] (bf16) ----
    {
        const int h = lane >> 3;
        const __hip_bfloat16* vbase = valp + lane;
        float acc = 0.f;
#pragma unroll
        for (int l = 0; l < NL; l++) {
#pragma unroll
            for (int p = 0; p < NP; p++) {
                const int idx = ((w * 5 + l) * 4 + p) * 8 + h;
                const int4 co = *(const int4*)dco[idx];
                const uint2 dw = dwp[idx];
                acc = fmaf(lo16f(dw.x), b2f(vbase[co.x]), acc);
                acc = fmaf(hi16f(dw.x), b2f(vbase[co.y]), acc);
                acc = fmaf(lo16f(dw.y), b2f(vbase[co.z]), acc);
                acc = fmaf(hi16f(dw.y), b2f(vbase[co.w]), acc);
            }
        }
        qb[w][lane] = __float2bfloat16(acc);   // rows 4-15 remain zero
    }
    __syncthreads();

    // ---- phase D: attn @ Wout + bout via MFMA (wave w owns ntile w) ----
    {
        f32x4 acc = {0.f, 0.f, 0.f, 0.f};
#pragma unroll
        for (int kc = 0; kc < 2; kc++) {
            const short8 a = *(const short8*)&qb[m16][kc * 32 + qd * 8];
            const short8 b = *(const short8*)(Woutp + ((size_t)(w * 2 + kc) * 64 + lane) * 8);
            acc = __builtin_amdgcn_mfma_f32_16x16x32_bf16(a, b, acc, 0, 0, 0);
        }
        if (qd == 0) {
            const int n = w * 16 + m16;
            const float bn = bout[n];
#pragma unroll
            for (int r = 0; r < 4; r++) xs4[r][n] = acc[r] + bn;
        }
    }
    __syncthreads();

    // ---- LN1 (wave w = query w); residual qf; store x1 ----
    {
        const float xpre = qf + xs4[w][lane];
        float s = xpre, s2 = xpre * xpre;
#pragma unroll
        for (int o = 32; o >= 1; o >>= 1) {
            s += __shfl_xor(s, o, 64);
            s2 += __shfl_xor(s2, o, 64);
        }
        const float mean = s * (1.f / 64.f);
        const float var = s2 * (1.f / 64.f) - mean * mean;
        const float xn = (xpre - mean) * rsqrtf(var + 1e-5f);
        xout[(size_t)qi * DM + lane] = xn * g1[lane] + b1[lane];
    }
}

// ---- kernel 4: FFN via MFMA, 32 queries/block, hidden in 4 quarters; 29.7 KB LDS ----
__global__ void __launch_bounds__(256)
ffn_kernel(const __hip_bfloat16* __restrict__ W1p, const float* __restrict__ bff1,
           const __hip_bfloat16* __restrict__ W2p, const float* __restrict__ bff2,
           const float* __restrict__ g2, const float* __restrict__ b2,
           float* __restrict__ io) {
    __shared__ __align__(16) __hip_bfloat16 xb[32][72];    // 4608 B
    __shared__ __align__(16) __hip_bfloat16 hb[32][264];   // 16896 B (256 cols + pad)
    __shared__ __align__(16) float yr[32][64];             // 8192 B

    const int tid = threadIdx.x;
    const int lane = tid & 63;
    const int w = tid >> 6;
    const int m16 = lane & 15, qd = lane >> 4;
    const int q0 = blockIdx.x * 32;

    // ---- load x1: thread t -> query t>>3, cols (t&7)*8 .. +7 (bf16 only; f32 reloaded at LN) ----
    {
        const int q = tid >> 3, i = tid & 7;
        const float4 v0 = *(const float4*)&io[(size_t)(q0 + q) * DM + i * 8];
        const float4 v1 = *(const float4*)&io[(size_t)(q0 + q) * DM + i * 8 + 4];
        __hip_bfloat16* xp = &xb[q][i * 8];
        xp[0] = __float2bfloat16(v0.x); xp[1] = __float2bfloat16(v0.y);
        xp[2] = __float2bfloat16(v0.z); xp[3] = __float2bfloat16(v0.w);
        xp[4] = __float2bfloat16(v1.x); xp[5] = __float2bfloat16(v1.y);
        xp[6] = __float2bfloat16(v1.z); xp[7] = __float2bfloat16(v1.w);
    }
    __syncthreads();

    f32x4 yacc[2];
    yacc[0] = (f32x4){0.f, 0.f, 0.f, 0.f};
    yacc[1] = (f32x4){0.f, 0.f, 0.f, 0.f};

#pragma unroll
    for (int qtr = 0; qtr < 4; qtr++) {
        // GEMM1 quarter: hidden cols [qtr*256, +256); wave w does ntiles qtr*16 + w + 4*ti
#pragma unroll
        for (int ti = 0; ti < 4; ti++) {
            const int nt = qtr * 16 + w + ti * 4;
            f32x4 acc[2];
            acc[0] = (f32x4){0.f, 0.f, 0.f, 0.f};
            acc[1] = (f32x4){0.f, 0.f, 0.f, 0.f};
#pragma unroll
            for (int kc = 0; kc < 2; kc++) {
                const short8 b = *(const short8*)(W1p + ((size_t)(nt * 2 + kc) * 64 + lane) * 8);
#pragma unroll
                for (int mt = 0; mt < 2; mt++) {
                    const short8 a = *(const short8*)&xb[mt * 16 + m16][kc * 32 + qd * 8];
                    acc[mt] = __builtin_amdgcn_mfma_f32_16x16x32_bf16(a, b, acc[mt], 0, 0, 0);
                }
            }
            const int ncol = (nt - qtr * 16) * 16 + m16;   // 0..255
            const float bn = bff1[nt * 16 + m16];
#pragma unroll
            for (int mt = 0; mt < 2; mt++)
#pragma unroll
                for (int r = 0; r < 4; r++)
                    hb[mt * 16 + qd * 4 + r][ncol] = __float2bfloat16(fmaxf(acc[mt][r] + bn, 0.f));
        }
        __syncthreads();
        // GEMM2 partial: wave w owns y-ntile w; this quarter's 8 kchunks
#pragma unroll
        for (int kc2 = 0; kc2 < 8; kc2++) {
            const short8 b = *(const short8*)(W2p + ((size_t)(w * 32 + qtr * 8 + kc2) * 64 + lane) * 8);
#pragma unroll
            for (int mt = 0; mt < 2; mt++) {
                const short8 a = *(const short8*)&hb[mt * 16 + m16][kc2 * 32 + qd * 8];
                yacc[mt] = __builtin_amdgcn_mfma_f32_16x16x32_bf16(a, b, yacc[mt], 0, 0, 0);
            }
        }
        __syncthreads();   // hb consumed before next quarter overwrites
    }

    // ---- Y + bff2 (x1 residual re-read from io at LN stage) ----
    {
        const int n = w * 16 + m16;
        const float bn = bff2[n];
#pragma unroll
        for (int mt = 0; mt < 2; mt++)
#pragma unroll
            for (int r = 0; r < 4; r++) {
                const int mm = mt * 16 + qd * 4 + r;
                yr[mm][n] = yacc[mt][r] + bn;
            }
    }
    __syncthreads();

    // ---- LN2 + store: thread t -> query t>>3, cols (t&7)*8..+7; 8-lane reduce ----
    {
        const int q = tid >> 3, i = tid & 7;
        const float4 x0 = *(const float4*)&io[(size_t)(q0 + q) * DM + i * 8];
        const float4 x1 = *(const float4*)&io[(size_t)(q0 + q) * DM + i * 8 + 4];
        float4 v0 = *(const float4*)&yr[q][i * 8];
        float4 v1 = *(const float4*)&yr[q][i * 8 + 4];
        v0.x += x0.x; v0.y += x0.y; v0.z += x0.z; v0.w += x0.w;
        v1.x += x1.x; v1.y += x1.y; v1.z += x1.z; v1.w += x1.w;
        float s = v0.x + v0.y + v0.z + v0.w + v1.x + v1.y + v1.z + v1.w;
        float s2 = v0.x * v0.x + v0.y * v0.y + v0.z * v0.z + v0.w * v0.w
                 + v1.x * v1.x + v1.y * v1.y + v1.z * v1.z + v1.w * v1.w;
#pragma unroll
        for (int o = 4; o >= 1; o >>= 1) { s += __shfl_xor(s, o, 64); s2 += __shfl_xor(s2, o, 64); }
        const float mean = s * (1.f / 64.f);
        const float var = s2 * (1.f / 64.f) - mean * mean;
        const float rstd = rsqrtf(var + 1e-5f);
        const float4 ga = *(const float4*)&g2[i * 8];
        const float4 gb = *(const float4*)&g2[i * 8 + 4];
        const float4 ba4 = *(const float4*)&b2[i * 8];
        const float4 bb4 = *(const float4*)&b2[i * 8 + 4];
        float4 o0, o1;
        o0.x = (v0.x - mean) * rstd * ga.x + ba4.x;
        o0.y = (v0.y - mean) * rstd * ga.y + ba4.y;
        o0.z = (v0.z - mean) * rstd * ga.z + ba4.z;
        o0.w = (v0.w - mean) * rstd * ga.w + ba4.w;
        o1.x = (v1.x - mean) * rstd * gb.x + bb4.x;
        o1.y = (v1.y - mean) * rstd * gb.y + bb4.y;
        o1.z = (v1.z - mean) * rstd * gb.z + bb4.z;
        o1.w = (v1.w - mean) * rstd * gb.w + bb4.w;
        *(float4*)&io[(size_t)(q0 + q) * DM + i * 8] = o0;
        *(float4*)&io[(size_t)(q0 + q) * DM + i * 8 + 4] = o1;
    }
}

extern "C" void kernel_launch(void* const* d_in, const int* in_sizes, int n_in,
                              void* d_out, int out_size, void* d_ws, size_t ws_size,
                              hipStream_t stream) {
    const int B0 = (in_sizes[4] >= 4096) ? 4 : 6;   // int side-inputs present -> 6
    const float* q_feat = (const float*)d_in[0];
    const float* dvf    = (const float*)d_in[1];
    const float* refp   = (const float*)d_in[2];
    const float* q_pos  = (const float*)d_in[3];
    const float* Wv   = (const float*)d_in[B0 + 0];
    const float* bv   = (const float*)d_in[B0 + 1];
    const float* Wo   = (const float*)d_in[B0 + 2];
    const float* bo   = (const float*)d_in[B0 + 3];
    const float* Wa   = (const float*)d_in[B0 + 4];
    const float* ba   = (const float*)d_in[B0 + 5];
    const float* Wout = (const float*)d_in[B0 + 6];
    const float* bout = (const float*)d_in[B0 + 7];
    const float* g1   = (const float*)d_in[B0 + 8];
    const float* b1   = (const float*)d_in[B0 + 9];
    const float* W1   = (const float*)d_in[B0 + 10];
    const float* bff1 = (const float*)d_in[B0 + 11];
    const float* W2   = (const float*)d_in[B0 + 12];
    const float* bff2 = (const float*)d_in[B0 + 13];
    const float* g2   = (const float*)d_in[B0 + 14];
    const float* b2   = (const float*)d_in[B0 + 15];
    float* out = (float*)d_out;

    const size_t val_elems = (size_t)LIN * DM;
    const size_t pack_elems = (size_t)(128 + 128 + 60 + 8) * 64 * 8;   // 165888 bf16
    const bool dbuf = ws_size >= (pack_elems + 2 * val_elems) * sizeof(__hip_bfloat16);

    __hip_bfloat16* W1p = (__hip_bfloat16*)d_ws;
    __hip_bfloat16* W2p = W1p + (size_t)128 * 64 * 8;
    __hip_bfloat16* Woap = W2p + (size_t)128 * 64 * 8;
    __hip_bfloat16* Woutp = Woap + (size_t)60 * 64 * 8;
    __hip_bfloat16* val0 = W1p + pack_elems;
    __hip_bfloat16* val1 = dbuf ? val0 + val_elems : val0;

    pack_kernel<<<81, 256, 0, stream>>>(W1, W2, Wo, Wa, Wout, W1p, W2p, Woap, Woutp);

    if (dbuf) {
        val_proj_kernel<<<(2 * LIN + 63) / 64, 256, 0, stream>>>(
            dvf, Wv, bv, val0, val1, 2 * LIN);
        attn4_kernel<<<(NB * NQ) / 4, 256, 0, stream>>>(
            q_feat, refp, q_pos, Woap, bo, ba, Woutp, bout, g1, b1,
            val0, val1, 0, out);
    } else {
        for (int b = 0; b < NB; b++) {
            val_proj_kernel<<<(LIN + 63) / 64, 256, 0, stream>>>(
                dvf + (size_t)b * val_elems, Wv, bv, val0, val0, LIN);
            attn4_kernel<<<NQ / 4, 256, 0, stream>>>(
                q_feat, refp, q_pos, Woap, bo, ba, Woutp, bout, g1, b1,
                val0, val0, b * NQ, out);
        }
    }
    ffn_kernel<<<(NB * NQ) / 32, 256, 0, stream>>>(W1p, bff1, W2p, bff2, g2, b2, out);
}